// Round 18
// baseline (322.590 us; speedup 1.0000x reference)
//
#include <hip/hip_runtime.h>

typedef unsigned short u16;
typedef unsigned int   u32;
typedef __attribute__((ext_vector_type(8))) short bfrag8;   // 8 x bf16
typedef __attribute__((ext_vector_type(4))) float f32x4;

#define NSAMP  15552
#define GRID_B 3888    // 3888 blocks * 4 waves * 1 sample = 15552
#define GRID_G 4131    // 4131 blocks * 4 waves * 16 rows = 264384 = NSAMP*17

__device__ __forceinline__ u32 bfr(float f){            // f32 -> bf16 bits, RNE
  u32 u = __float_as_uint(f);
  return (u + 0x7FFFu + ((u >> 16) & 1u)) >> 16;
}
__device__ __forceinline__ u32 packbf(float lo, float hi){
  return bfr(lo) | (bfr(hi) << 16);
}
__device__ __forceinline__ float ubf(u32 v){ return __uint_as_float(v << 16); }
__device__ __forceinline__ float ubfh(u32 v){ return __uint_as_float(v & 0xFFFF0000u); }
__device__ __forceinline__ float sigm(float v){ return 1.0f / (1.0f + __expf(-v)); }
__device__ __forceinline__ float softp(float v){ return (v > 20.f) ? v : log1pf(__expf(v)); }

// ---------------- Kernel A: W transpose->bf16, comb matrix, zero BN acc ----
__global__ void kA(const float* __restrict__ W, const float* __restrict__ al1,
                   const float* __restrict__ al2, const float* __restrict__ w1,
                   const float* __restrict__ w2, const float* __restrict__ a1b,
                   const float* __restrict__ a2b, u16* __restrict__ wt,
                   float* __restrict__ comb, float* __restrict__ mid){
  int idx = blockIdx.x * 256 + threadIdx.x;      // grid 64 -> 16384 elements
  int k = idx >> 7, n = idx & 127;
  wt[n * 128 + k] = (u16)bfr(W[idx]);            // WT[n][k] = W[k][n]
  if (blockIdx.x == 1) mid[threadIdx.x] = 0.f;   // zero BN accumulators (replay-safe)
  if (blockIdx.x == 0){
    float s1 = softp(w1[0]);
    float s2 = softp(w2[0]);
    for (int p = threadIdx.x; p < 289; p += 256){
      int i = p / 17, j = p - i * 17;
      float mij = s1 * (a1b[i*17+j] + sigm(al1[i*17+j])) + s2 * (a2b[i*17+j] + sigm(al2[i*17+j]));
      float mji = s1 * (a1b[j*17+i] + sigm(al1[j*17+i])) + s2 * (a2b[j*17+i] + sigm(al2[j*17+i]));
      comb[i*20 + j] = 0.5f * (mij + mji);
    }
  }
}

// ---------------- Kernel Q: Gram + norms + gates via MFMA (r10-verified) ----
struct __align__(16) QSmem { u16 xb[4][18][136]; };   // 19584 B -> 8 blocks/CU = 156.7 KB
__global__ __launch_bounds__(256, 8) void kQ(const float* __restrict__ x,
    const float* __restrict__ gw, const float* __restrict__ gb,
    float* __restrict__ gbuf){
  __shared__ QSmem q;
  const int tid = threadIdx.x;
  const int w  = tid >> 6;
  const int l  = tid & 63;
  const int g4 = l >> 4;
  const int lc = l & 15;
  const int s  = blockIdx.x * 4 + w;
  const float* xs = x + (size_t)s * 2176;

  float2 g2 = *(const float2*)(gw + 2*l);
  *(u32*)&q.xb[w][17][2*l] = packbf(g2.x, g2.y);   // row 17 = gate_w
  #pragma unroll
  for (int j = 0; j < 17; j++){
    float2 v = *(const float2*)(xs + j*128 + 2*l);
    *(u32*)&q.xb[w][j][2*l] = packbf(v.x, v.y);
  }
  __syncthreads();
  __builtin_amdgcn_sched_barrier(0);               // anti-hoist hygiene

  const int rB = 16 + ((lc < 2) ? lc : 1);         // B rows: 16=x16, 17=gate (clamped)
  f32x4 z4 = {0.f,0.f,0.f,0.f};
  f32x4 dg00 = z4, dg01 = z4, dg11 = z4;
  #pragma unroll
  for (int ks = 0; ks < 4; ks++){
    const int ko = ks*32 + (g4 << 3);
    bfrag8 a0 = *(const bfrag8*)&q.xb[w][lc][ko];
    bfrag8 a1 = *(const bfrag8*)&q.xb[w][rB][ko];
    dg00 = __builtin_amdgcn_mfma_f32_16x16x32_bf16(a0, a0, dg00, 0,0,0);
    dg01 = __builtin_amdgcn_mfma_f32_16x16x32_bf16(a0, a1, dg01, 0,0,0);
    dg11 = __builtin_amdgcn_mfma_f32_16x16x32_bf16(a1, a1, dg11, 0,0,0);
  }
  float* gs = gbuf + (size_t)s * 384;
  const float gbv = gb[0];
  #pragma unroll
  for (int r = 0; r < 4; r++){
    const int i = (g4 << 2) + r;
    gs[i*20 + lc] = dg00[r];                       // dot(x_i, x_lc)
    if (lc == 0){ gs[i*20 + 16] = dg01[r]; gs[16*20 + i] = dg01[r]; }
    if (lc == 1){ gs[360 + i] = sigm(dg01[r] + gbv); }
  }
  if ((lc >> 2) == g4){
    float v = dg00[lc & 3];
    gs[340 + lc] = 1.0f / fmaxf(sqrtf(v), 1e-12f);
  }
  if (l == 0) gs[340 + 16] = 1.0f / fmaxf(sqrtf(dg11[0]), 1e-12f);
  if (l == 1) gs[360 + 16] = sigm(dg11[0] + gbv);
}

// ---------------- shared LDS layout for kB variants ----
struct WaveMem {
  float G[17][20];      // Gram dots -> overwritten by A_hat    1360 B
  float scr[64];        // [0..16] inv-norm, [20..36] gate, [40..56] d
};                      // 1616 B
struct BSmem {
  WaveMem wm[4];        // 6464
  float   combs[340];   // 1360  -> 7824 B total
};
static_assert(sizeof(BSmem) <= 81920, "LDS budget");

// ---- common body: loads G/scr from gbuf, computes A_hat, emits z. ZOUT:
// 0 -> f32 into out, 1 -> bf16 into zbuf
template<int ZOUT>
__device__ __forceinline__ void kBl_body(
    const float* __restrict__ x, const float* __restrict__ combg,
    const float* __restrict__ gbuf, float* __restrict__ out,
    u16* __restrict__ zbuf){
  __shared__ BSmem sm;
  const int tid = threadIdx.x;
  const int w  = tid >> 6;
  const int l  = tid & 63;
  const int g4 = l >> 4;
  const int lc = l & 15;

  for (int p = tid; p < 340; p += 256) sm.combs[p] = combg[p];

  WaveMem& M = sm.wm[w];
  float* Mf = (float*)&M.G[0][0];
  const int s = blockIdx.x * 4 + w;
  const float* gs = gbuf + (size_t)s * 384;
  for (int p = l; p < 380; p += 64) Mf[p] = gs[p];

  const float* xs = x + (size_t)s * 2176;
  float2 xr[17];
  #pragma unroll
  for (int j = 0; j < 17; j++) xr[j] = *(const float2*)(xs + j*128 + 2*l);
  __syncthreads();   // (1) comb + G + scr staged

  // P2: A construct + degree
  const float iv16 = M.scr[16], gt16 = M.scr[36];
  const float ivj  = M.scr[lc];
  float av00[4], av01[4], dp0[4];
  #pragma unroll
  for (int r = 0; r < 4; r++){
    const int i0 = (g4 << 2) + r;
    const float iv0 = M.scr[i0], gi0 = M.scr[20 + i0];
    float dyn = (i0 == lc) ? 2.0f : fmaxf(M.G[i0][lc] * iv0 * ivj, 0.f);
    av00[r] = gi0 * sm.combs[i0*20 + lc] + (1.f - gi0) * dyn;
    float dyn16 = fmaxf(M.G[i0][16] * iv0 * iv16, 0.f);
    float a16 = gi0 * sm.combs[i0*20 + 16] + (1.f - gi0) * dyn16;
    av01[r] = (lc == 0) ? a16 : 0.f;
    dp0[r] = av00[r] + av01[r];
  }
  float dyn10 = fmaxf(M.G[16][lc] * iv16 * ivj, 0.f);
  float av10 = gt16 * sm.combs[16*20 + lc] + (1.f - gt16) * dyn10;
  float av11 = (lc == 0) ? (gt16 * sm.combs[16*20 + 16] + (1.f - gt16) * 2.0f) : 0.f;
  float dp1 = av10 + av11;
  #pragma unroll
  for (int m = 1; m <= 8; m <<= 1){
    #pragma unroll
    for (int r = 0; r < 4; r++) dp0[r] += __shfl_xor(dp0[r], m, 64);
    dp1 += __shfl_xor(dp1, m, 64);
  }
  float dd0[4];
  #pragma unroll
  for (int r = 0; r < 4; r++) dd0[r] = rsqrtf(dp0[r] + 1e-6f);
  float dd1 = rsqrtf(dp1 + 1e-6f);
  if (lc == 0){
    #pragma unroll
    for (int r = 0; r < 4; r++) M.scr[40 + (g4<<2) + r] = dd0[r];
  }
  if (l == 0) M.scr[40 + 16] = dd1;
  __syncthreads();   // (2) d ready

  // P3: A_hat in place over G
  const float dj0 = M.scr[40 + lc];
  const float dj1 = M.scr[40 + 16];
  #pragma unroll
  for (int r = 0; r < 4; r++){
    const int i0 = (g4 << 2) + r;
    M.G[i0][lc] = dd0[r] * av00[r] * dj0;
    if (lc == 0) M.G[i0][16] = dd0[r] * av01[r] * dj1;
  }
  if (g4 == 0) M.G[16][lc] = dd1 * av10 * dj0;
  if (l == 0)  M.G[16][16] = dd1 * av11 * dj1;
  __syncthreads();   // (3) A_hat ready

  // P4: z = A_hat @ x
  float* ob = out + (size_t)s * 2176;
  u16*   zb = zbuf + (size_t)s * 2176;
  for (int i = 0; i < 17; i++){
    const float4 a0 = *(const float4*)&M.G[i][0];
    const float4 a1 = *(const float4*)&M.G[i][4];
    const float4 a2 = *(const float4*)&M.G[i][8];
    const float4 a3 = *(const float4*)&M.G[i][12];
    const float a16 = M.G[i][16];
    float zx = a0.x*xr[0].x,  zy = a0.x*xr[0].y;
    zx += a0.y*xr[1].x;  zy += a0.y*xr[1].y;
    zx += a0.z*xr[2].x;  zy += a0.z*xr[2].y;
    zx += a0.w*xr[3].x;  zy += a0.w*xr[3].y;
    zx += a1.x*xr[4].x;  zy += a1.x*xr[4].y;
    zx += a1.y*xr[5].x;  zy += a1.y*xr[5].y;
    zx += a1.z*xr[6].x;  zy += a1.z*xr[6].y;
    zx += a1.w*xr[7].x;  zy += a1.w*xr[7].y;
    zx += a2.x*xr[8].x;  zy += a2.x*xr[8].y;
    zx += a2.y*xr[9].x;  zy += a2.y*xr[9].y;
    zx += a2.z*xr[10].x; zy += a2.z*xr[10].y;
    zx += a2.w*xr[11].x; zy += a2.w*xr[11].y;
    zx += a3.x*xr[12].x; zy += a3.x*xr[12].y;
    zx += a3.y*xr[13].x; zy += a3.y*xr[13].y;
    zx += a3.z*xr[14].x; zy += a3.z*xr[14].y;
    zx += a3.w*xr[15].x; zy += a3.w*xr[15].y;
    zx += a16*xr[16].x;  zy += a16*xr[16].y;
    if (ZOUT == 1){
      *(u32*)&zb[i*128 + 2*l] = packbf(zx, zy);
    } else {
      float2 zv; zv.x = zx; zv.y = zy;
      *(float2*)&ob[i*128 + 2*l] = zv;
    }
  }
}

__global__ __launch_bounds__(256, 8) void kBl2(
    const float* __restrict__ x, const float* __restrict__ combg,
    const float* __restrict__ gbuf, u16* __restrict__ zbuf){
  kBl_body<1>(x, combg, gbuf, nullptr, zbuf);
}
__global__ __launch_bounds__(256, 8) void kBl(
    const float* __restrict__ x, const float* __restrict__ combg,
    const float* __restrict__ gbuf, float* __restrict__ out){
  kBl_body<0>(x, combg, gbuf, out, nullptr);
}

// ---------------- Kernel Bf: monolithic fallback (ws too small; r9-verified) ----
__global__ __launch_bounds__(256, 4) void kBf(
    const float* __restrict__ x, const float* __restrict__ gw,
    const float* __restrict__ gb, const float* __restrict__ combg,
    float* __restrict__ out){
  __shared__ BSmem sm;
  const int tid = threadIdx.x;
  const int w  = tid >> 6;
  const int l  = tid & 63;
  const int g4 = l >> 4;
  const int lc = l & 15;

  for (int p = tid; p < 340; p += 256) sm.combs[p] = combg[p];
  __syncthreads();

  WaveMem& M = sm.wm[w];
  float2 g2 = *(const float2*)(gw + 2*l);
  const float gbv = gb[0];
  const int s = blockIdx.x * 4 + w;
  const float* xs = x + (size_t)s * 2176;
  float2 xr[17];
  #pragma unroll
  for (int j = 0; j < 17; j++) xr[j] = *(const float2*)(xs + j*128 + 2*l);

  #pragma unroll
  for (int i = 0; i < 17; i++){
    float p[17];
    #pragma unroll
    for (int j = i; j < 17; j++)
      p[j-i] = xr[i].x*xr[j].x + xr[i].y*xr[j].y;
    float pg = xr[i].x*g2.x + xr[i].y*g2.y;
    #pragma unroll
    for (int m = 1; m <= 32; m <<= 1){
      #pragma unroll
      for (int j = i; j < 17; j++) p[j-i] += __shfl_xor(p[j-i], m, 64);
      pg += __shfl_xor(pg, m, 64);
    }
    #pragma unroll
    for (int j = i; j < 17; j++){
      if (l == j) M.G[i][j] = p[j-i];
      if (i != j && l == i) M.G[j][i] = p[j-i];
    }
    if (l == i){
      M.scr[i]      = 1.0f / fmaxf(sqrtf(p[0]), 1e-12f);
      M.scr[20 + i] = sigm(pg + gbv);
    }
  }
  __syncthreads();

  const float iv16 = M.scr[16], gt16 = M.scr[36];
  const float ivj  = M.scr[lc];
  float av00[4], av01[4], dp0[4];
  #pragma unroll
  for (int r = 0; r < 4; r++){
    const int i0 = (g4 << 2) + r;
    const float iv0 = M.scr[i0], gi0 = M.scr[20 + i0];
    float dyn = (i0 == lc) ? 2.0f : fmaxf(M.G[i0][lc] * iv0 * ivj, 0.f);
    av00[r] = gi0 * sm.combs[i0*20 + lc] + (1.f - gi0) * dyn;
    float dyn16 = fmaxf(M.G[i0][16] * iv0 * iv16, 0.f);
    float a16 = gi0 * sm.combs[i0*20 + 16] + (1.f - gi0) * dyn16;
    av01[r] = (lc == 0) ? a16 : 0.f;
    dp0[r] = av00[r] + av01[r];
  }
  float dyn10 = fmaxf(M.G[16][lc] * iv16 * ivj, 0.f);
  float av10 = gt16 * sm.combs[16*20 + lc] + (1.f - gt16) * dyn10;
  float av11 = (lc == 0) ? (gt16 * sm.combs[16*20 + 16] + (1.f - gt16) * 2.0f) : 0.f;
  float dp1 = av10 + av11;
  #pragma unroll
  for (int m = 1; m <= 8; m <<= 1){
    #pragma unroll
    for (int r = 0; r < 4; r++) dp0[r] += __shfl_xor(dp0[r], m, 64);
    dp1 += __shfl_xor(dp1, m, 64);
  }
  float dd0[4];
  #pragma unroll
  for (int r = 0; r < 4; r++) dd0[r] = rsqrtf(dp0[r] + 1e-6f);
  float dd1 = rsqrtf(dp1 + 1e-6f);
  if (lc == 0){
    #pragma unroll
    for (int r = 0; r < 4; r++) M.scr[40 + (g4<<2) + r] = dd0[r];
  }
  if (l == 0) M.scr[40 + 16] = dd1;
  __syncthreads();

  const float dj0 = M.scr[40 + lc];
  const float dj1 = M.scr[40 + 16];
  #pragma unroll
  for (int r = 0; r < 4; r++){
    const int i0 = (g4 << 2) + r;
    M.G[i0][lc] = dd0[r] * av00[r] * dj0;
    if (lc == 0) M.G[i0][16] = dd0[r] * av01[r] * dj1;
  }
  if (g4 == 0) M.G[16][lc] = dd1 * av10 * dj0;
  if (l == 0)  M.G[16][16] = dd1 * av11 * dj1;
  __syncthreads();

  float* ob = out + (size_t)s * 2176;
  for (int i = 0; i < 17; i++){
    const float4 a0 = *(const float4*)&M.G[i][0];
    const float4 a1 = *(const float4*)&M.G[i][4];
    const float4 a2 = *(const float4*)&M.G[i][8];
    const float4 a3 = *(const float4*)&M.G[i][12];
    const float a16 = M.G[i][16];
    float zx = a0.x*xr[0].x,  zy = a0.x*xr[0].y;
    zx += a0.y*xr[1].x;  zy += a0.y*xr[1].y;
    zx += a0.z*xr[2].x;  zy += a0.z*xr[2].y;
    zx += a0.w*xr[3].x;  zy += a0.w*xr[3].y;
    zx += a1.x*xr[4].x;  zy += a1.x*xr[4].y;
    zx += a1.y*xr[5].x;  zy += a1.y*xr[5].y;
    zx += a1.z*xr[6].x;  zy += a1.z*xr[6].y;
    zx += a1.w*xr[7].x;  zy += a1.w*xr[7].y;
    zx += a2.x*xr[8].x;  zy += a2.x*xr[8].y;
    zx += a2.y*xr[9].x;  zy += a2.y*xr[9].y;
    zx += a2.z*xr[10].x; zy += a2.z*xr[10].y;
    zx += a2.w*xr[11].x; zy += a2.w*xr[11].y;
    zx += a3.x*xr[12].x; zy += a3.x*xr[12].y;
    zx += a3.y*xr[13].x; zy += a3.y*xr[13].y;
    zx += a3.z*xr[14].x; zy += a3.z*xr[14].y;
    zx += a3.w*xr[15].x; zy += a3.w*xr[15].y;
    zx += a16*xr[16].x;  zy += a16*xr[16].y;
    float2 zv; zv.x = zx; zv.y = zy;
    *(float2*)&ob[i*128 + 2*l] = zv;
  }
}

// ---------------- Kernel G6: coalesced streaming MFMA GEMM (LDS overlay z/h) ----
struct __align__(16) G6Smem {
  u16   zh[4][16][136];  // 17408 B  z tile in -> h tile out (overlay; per-wave)
  float stash[4][256];   // 4096 B
};                       // 21504 B -> 7 blocks/CU
__global__ __launch_bounds__(256, 7) void kG6(const u16* __restrict__ wtg,
    u16* __restrict__ zbuf, float* __restrict__ part){
  __shared__ G6Smem g;
  const int tid = threadIdx.x;
  const int w  = tid >> 6;
  const int l  = tid & 63;
  const int g4 = l >> 4;
  const int lc = l & 15;
  const int tile = blockIdx.x * 4 + w;           // 4131*4 = 16524 tiles exactly
  u16* zt = zbuf + (size_t)tile * 2048;          // 16 rows * 128 ch

  // P0: coalesced tile load (lane l: bytes [k*1024 + l*16, +16))
  uint4 zc[4];
  #pragma unroll
  for (int k = 0; k < 4; k++)
    zc[k] = *(const uint4*)((const char*)zt + k*1024 + l*16);
  // chunk (k,l) = row k*4 + (l>>4), cols (l&15)*8 .. +8
  #pragma unroll
  for (int k = 0; k < 4; k++)
    *(uint4*)&g.zh[w][k*4 + (l>>4)][(l&15)*8] = zc[k];
  asm volatile("s_waitcnt lgkmcnt(0)" ::: "memory");
  __builtin_amdgcn_sched_barrier(0);             // cross-lane LDS handoff (rule #18)

  // P1: A-fragments from LDS (2-way bank, free). Data lands in regs; the
  // later overlay writes are ordered after these reads by data dependence.
  bfrag8 zf[4];
  #pragma unroll
  for (int ks = 0; ks < 4; ks++)
    zf[ks] = *(const bfrag8*)&g.zh[w][lc][ks*32 + (g4 << 3)];

  // P2: MFMA (B = W^T rows from global; 32 KB, L1/L2-hot)
  f32x4 zero4 = {0.f,0.f,0.f,0.f};
  f32x4 acc[8];
  #pragma unroll
  for (int nf = 0; nf < 8; nf++) acc[nf] = zero4;
  #pragma unroll
  for (int nf = 0; nf < 8; nf++){
    const u16* wr = &wtg[(nf*16 + lc)*128 + (g4 << 3)];
    bfrag8 w0 = *(const bfrag8*)&wr[0];
    bfrag8 w1 = *(const bfrag8*)&wr[32];
    bfrag8 w2 = *(const bfrag8*)&wr[64];
    bfrag8 w3 = *(const bfrag8*)&wr[96];
    acc[nf] = __builtin_amdgcn_mfma_f32_16x16x32_bf16(zf[0], w0, acc[nf], 0,0,0);
    acc[nf] = __builtin_amdgcn_mfma_f32_16x16x32_bf16(zf[1], w1, acc[nf], 0,0,0);
    acc[nf] = __builtin_amdgcn_mfma_f32_16x16x32_bf16(zf[2], w2, acc[nf], 0,0,0);
    acc[nf] = __builtin_amdgcn_mfma_f32_16x16x32_bf16(zf[3], w3, acc[nf], 0,0,0);
  }

  // P3: BN partials (exact f32) + h -> LDS bf16 overlay (hyp1: row 4*g4+r, col nf*16+lc)
  float s[8], q[8];
  #pragma unroll
  for (int nf = 0; nf < 8; nf++){
    float ss = 0.f, qq = 0.f;
    #pragma unroll
    for (int r = 0; r < 4; r++){
      float v = acc[nf][r];
      g.zh[w][4*g4 + r][nf*16 + lc] = (u16)bfr(v);
      ss += v; qq += v*v;
    }
    ss += __shfl_xor(ss, 16, 64); ss += __shfl_xor(ss, 32, 64);
    qq += __shfl_xor(qq, 16, 64); qq += __shfl_xor(qq, 32, 64);
    s[nf] = ss; q[nf] = qq;
  }
  asm volatile("s_waitcnt lgkmcnt(0)" ::: "memory");
  __builtin_amdgcn_sched_barrier(0);             // cross-lane LDS handoff

  // P4: coalesced store (lane l: bytes [k*1024 + l*16, +16) of the tile)
  #pragma unroll
  for (int k = 0; k < 4; k++){
    uint4 pv = *(const uint4*)&g.zh[w][k*4 + (l>>4)][(l&15)*8];
    *(uint4*)((char*)zt + k*1024 + l*16) = pv;   // in-place over own tile
  }

  // P5: BN partial block-reduce, contention-free part store
  if (l < 16){
    #pragma unroll
    for (int nf = 0; nf < 8; nf++){
      g.stash[w][nf*16 + l]       = s[nf];
      g.stash[w][128 + nf*16 + l] = q[nf];
    }
  }
  __syncthreads();
  part[(size_t)blockIdx.x * 256 + tid] =
      g.stash[0][tid] + g.stash[1][tid] + g.stash[2][tid] + g.stash[3][tid];
}

// ---------------- Kernel C: reduce per-block BN partials -> mid ----------------
__global__ __launch_bounds__(256) void kC(const float* __restrict__ part,
    float* __restrict__ mid, int nblk){
  __shared__ float smem[256];
  const int t = threadIdx.x, c = blockIdx.x;     // c = channel slot 0..255
  float acc = 0.f;
  for (int g = t; g < nblk; g += 256) acc += part[(size_t)g * 256 + c];
  smem[t] = acc;
  __syncthreads();
  for (int sft = 128; sft > 0; sft >>= 1){
    if (t < sft) smem[t] += smem[t + sft];
    __syncthreads();
  }
  if (t == 0) mid[c] = smem[0];
}

// ---------------- Kernel G2a: streaming GEMM + atomics (need2 fallback) ----
__global__ __launch_bounds__(256, 4) void kG2a(const u16* __restrict__ wtg,
    const u16* __restrict__ zbuf, float* __restrict__ mid, float* __restrict__ out){
  __shared__ float stash[4][256];
  const int tid = threadIdx.x;
  const int w  = tid >> 6;
  const int l  = tid & 63;
  const int g4 = l >> 4;
  const int lc = l & 15;
  const int R = blockIdx.x * 64 + w * 16;

  const u16* zr = zbuf + (size_t)R * 128;
  f32x4 zero4 = {0.f,0.f,0.f,0.f};
  f32x4 acc[8];
  #pragma unroll
  for (int nf = 0; nf < 8; nf++) acc[nf] = zero4;
  #pragma unroll
  for (int ks = 0; ks < 4; ks++){
    const int ko = ks*32 + (g4 << 3);
    bfrag8 za = *(const bfrag8*)&zr[lc * 128 + ko];
    #pragma unroll
    for (int nf = 0; nf < 8; nf++){
      bfrag8 bw = *(const bfrag8*)&wtg[(nf*16 + lc)*128 + ko];
      acc[nf] = __builtin_amdgcn_mfma_f32_16x16x32_bf16(za, bw, acc[nf], 0,0,0);
    }
  }
  float* hg = out + (size_t)R * 128;
  float s[8], q[8];
  #pragma unroll
  for (int nf = 0; nf < 8; nf++){
    float ss = 0.f, qq = 0.f;
    #pragma unroll
    for (int r = 0; r < 4; r++){
      float v = acc[nf][r];
      hg[(4*g4 + r)*128 + nf*16 + lc] = v;
      ss += v; qq += v*v;
    }
    ss += __shfl_xor(ss, 16, 64); ss += __shfl_xor(ss, 32, 64);
    qq += __shfl_xor(qq, 16, 64); qq += __shfl_xor(qq, 32, 64);
    s[nf] = ss; q[nf] = qq;
  }
  if (l < 16){
    #pragma unroll
    for (int nf = 0; nf < 8; nf++){
      stash[w][nf*16 + l]       = s[nf];
      stash[w][128 + nf*16 + l] = q[nf];
    }
  }
  __syncthreads();
  atomicAdd(&mid[tid], stash[0][tid] + stash[1][tid] + stash[2][tid] + stash[3][tid]);
}

// ---------------- Kernel G: r10 staged variant (fallback, atomics) ----------------
struct __align__(16) GSmem {
  u16 wl[128][132];
  u16 zl[4][16][132];
};
__global__ __launch_bounds__(256, 3) void kG(const u16* __restrict__ wtg,
    float* __restrict__ mid, float* __restrict__ out){
  __shared__ GSmem g;
  const int tid = threadIdx.x;
  const int w  = tid >> 6;
  const int l  = tid & 63;
  const int g4 = l >> 4;
  const int lc = l & 15;

  for (int p = tid; p < 8192; p += 256){
    int n = p >> 6, k2 = (p & 63) * 2;
    *(u32*)&g.wl[n][k2] = ((const u32*)wtg)[p];
  }
  const int R = blockIdx.x * 64 + w * 16;
  float* zg = out + (size_t)R * 128;
  #pragma unroll
  for (int r = 0; r < 16; r++){
    float2 zv = *(const float2*)&zg[r*128 + 2*l];
    *(u32*)&g.zl[w][r][2*l] = packbf(zv.x, zv.y);
  }
  __syncthreads();
  __builtin_amdgcn_sched_barrier(0);

  f32x4 zero4 = {0.f,0.f,0.f,0.f};
  f32x4 acc[8];
  #pragma unroll
  for (int nf = 0; nf < 8; nf++) acc[nf] = zero4;
  #pragma unroll
  for (int ks = 0; ks < 4; ks++){
    const int ko = ks*32 + (g4 << 3);
    bfrag8 za = *(const bfrag8*)&g.zl[w][lc][ko];
    #pragma unroll
    for (int nf = 0; nf < 8; nf++){
      bfrag8 bw = *(const bfrag8*)&g.wl[nf*16 + lc][ko];
      acc[nf] = __builtin_amdgcn_mfma_f32_16x16x32_bf16(za, bw, acc[nf], 0,0,0);
    }
  }

  float s[8], q[8];
  #pragma unroll
  for (int nf = 0; nf < 8; nf++){
    float ss = 0.f, qq = 0.f;
    #pragma unroll
    for (int r = 0; r < 4; r++){
      float v = acc[nf][r];
      zg[(4*g4 + r)*128 + nf*16 + lc] = v;
      ss += v; qq += v*v;
    }
    ss += __shfl_xor(ss, 16, 64); ss += __shfl_xor(ss, 32, 64);
    qq += __shfl_xor(qq, 16, 64); qq += __shfl_xor(qq, 32, 64);
    s[nf] = ss; q[nf] = qq;
  }

  __syncthreads();
  float* stash = (float*)&g.zl[w][0][0];
  if (l < 16){
    #pragma unroll
    for (int nf = 0; nf < 8; nf++){
      stash[nf*16 + l]       = s[nf];
      stash[128 + nf*16 + l] = q[nf];
    }
  }
  __syncthreads();
  float t0 = ((float*)&g.zl[0][0][0])[tid];
  float t1 = ((float*)&g.zl[1][0][0])[tid];
  float t2 = ((float*)&g.zl[2][0][0])[tid];
  float t3 = ((float*)&g.zl[3][0][0])[tid];
  atomicAdd(&mid[tid], t0 + t1 + t2 + t3);
}

// ---------------- Kernel D2: BN + ReLU + residual, h from bf16 buffer ----------------
__global__ __launch_bounds__(256) void kD2(const float* __restrict__ x,
    const float* __restrict__ mid, const float* __restrict__ gamma,
    const float* __restrict__ beta, const u16* __restrict__ hbuf,
    float* __restrict__ out){
  __shared__ float sc[128], sh[128];
  const int t = threadIdx.x;
  if (t < 128){
    const float ic = 1.0f / 264384.0f;     // N*J
    float mean = mid[t] * ic;
    float var  = fmaxf(mid[128 + t] * ic - mean*mean, 0.f);
    float scl  = gamma[t] * rsqrtf(var + 1e-5f);
    sc[t] = scl;
    sh[t] = beta[t] - mean * scl;
  }
  __syncthreads();
  const int total16 = 4230144;             // 33,841,152 / 8 channels per thread-iter
  for (int i = blockIdx.x*256 + t; i < total16; i += 2048*256){
    uint4 hv = ((const uint4*)hbuf)[i];
    float4 x0 = ((const float4*)x)[2*i];
    float4 x1 = ((const float4*)x)[2*i + 1];
    int c0 = (i & 15) << 3;
    float4 r0, r1;
    r0.x = fmaxf(ubf (hv.x)*sc[c0+0] + sh[c0+0], 0.f) + x0.x;
    r0.y = fmaxf(ubfh(hv.x)*sc[c0+1] + sh[c0+1], 0.f) + x0.y;
    r0.z = fmaxf(ubf (hv.y)*sc[c0+2] + sh[c0+2], 0.f) + x0.z;
    r0.w = fmaxf(ubfh(hv.y)*sc[c0+3] + sh[c0+3], 0.f) + x0.w;
    r1.x = fmaxf(ubf (hv.z)*sc[c0+4] + sh[c0+4], 0.f) + x1.x;
    r1.y = fmaxf(ubfh(hv.z)*sc[c0+5] + sh[c0+5], 0.f) + x1.y;
    r1.z = fmaxf(ubf (hv.w)*sc[c0+6] + sh[c0+6], 0.f) + x1.z;
    r1.w = fmaxf(ubfh(hv.w)*sc[c0+7] + sh[c0+7], 0.f) + x1.w;
    ((float4*)out)[2*i]     = r0;
    ((float4*)out)[2*i + 1] = r1;
  }
}

// ---------------- Kernel D: BN + ReLU + residual, h f32 in out (fallback) ----------------
__global__ __launch_bounds__(256) void kD(const float* __restrict__ x,
    const float* __restrict__ mid, const float* __restrict__ gamma,
    const float* __restrict__ beta, float* __restrict__ out){
  __shared__ float sc[128], sh[128];
  const int t = threadIdx.x;
  if (t < 128){
    const float ic = 1.0f / 264384.0f;     // N*J
    float mean = mid[t] * ic;
    float var  = fmaxf(mid[128 + t] * ic - mean*mean, 0.f);
    float scl  = gamma[t] * rsqrtf(var + 1e-5f);
    sc[t] = scl;
    sh[t] = beta[t] - mean * scl;
  }
  __syncthreads();
  const int total = 8460288;               // 33,841,152 / 4
  for (int i = blockIdx.x*256 + t; i < total; i += 2048*256){
    float4 h  = ((const float4*)out)[i];
    float4 xv = ((const float4*)x)[i];
    int c0 = (i & 31) << 2;
    float4 r;
    r.x = fmaxf(h.x*sc[c0+0] + sh[c0+0], 0.f) + xv.x;
    r.y = fmaxf(h.y*sc[c0+1] + sh[c0+1], 0.f) + xv.y;
    r.z = fmaxf(h.z*sc[c0+2] + sh[c0+2], 0.f) + xv.z;
    r.w = fmaxf(h.w*sc[c0+3] + sh[c0+3], 0.f) + xv.w;
    ((float4*)out)[i] = r;
  }
}

extern "C" void kernel_launch(void* const* d_in, const int* in_sizes, int n_in,
                              void* d_out, int out_size, void* d_ws, size_t ws_size,
                              hipStream_t stream){
  (void)in_sizes; (void)n_in; (void)out_size;
  const float* x     = (const float*)d_in[0];
  const float* W     = (const float*)d_in[1];
  // d_in[2] = b : cancelled exactly by training-mode BatchNorm (mean shift)
  const float* al1   = (const float*)d_in[3];
  const float* al2   = (const float*)d_in[4];
  const float* w1    = (const float*)d_in[5];
  const float* w2    = (const float*)d_in[6];
  const float* gw    = (const float*)d_in[7];
  const float* gb    = (const float*)d_in[8];
  const float* gamma = (const float*)d_in[9];
  const float* beta  = (const float*)d_in[10];
  const float* a1b   = (const float*)d_in[11];
  const float* a2b   = (const float*)d_in[12];
  float* out = (float*)d_out;

  float* wsf  = (float*)d_ws;        // comb 384 | wt 8192 | mid 256 | gbuf | zbuf | part
  float* comb = wsf;
  u16*   wt   = (u16*)(wsf + 384);
  float* mid  = wsf + 384 + 8192;
  float* gbuf = wsf + 384 + 8192 + 256;                    // 15552*384 f32 = 23.9 MB
  u16*   zbuf = (u16*)(gbuf + (size_t)NSAMP*384);          // 33,841,152 u16 = 67.7 MB
  float* part = (float*)(zbuf + (size_t)NSAMP*2176);       // 4131*256 f32 = 4.2 MB
  const size_t base  = (size_t)(384 + 8192 + 256) * 4;
  const size_t need1 = base + (size_t)NSAMP*384*4;                         // gbuf path
  const size_t need2 = need1 + (size_t)NSAMP*2176*2;                       // + zbuf path
  const size_t need3 = need2 + (size_t)GRID_G*256*4;                       // + part path

  hipLaunchKernelGGL(kA, dim3(64), dim3(256), 0, stream, W, al1, al2, w1, w2, a1b, a2b, wt, comb, mid);
  if (ws_size >= need3){
    hipLaunchKernelGGL(kQ,   dim3(GRID_B), dim3(256), 0, stream, x, gw, gb, gbuf);
    hipLaunchKernelGGL(kBl2, dim3(GRID_B), dim3(256), 0, stream, x, comb, gbuf, zbuf);
    hipLaunchKernelGGL(kG6,  dim3(GRID_G), dim3(256), 0, stream, wt, zbuf, part);
    hipLaunchKernelGGL(kC,   dim3(256),    dim3(256), 0, stream, part, mid, GRID_G);
    hipLaunchKernelGGL(kD2,  dim3(2048),   dim3(256), 0, stream, x, mid, gamma, beta, zbuf, out);
  } else if (ws_size >= need2){
    hipLaunchKernelGGL(kQ,   dim3(GRID_B), dim3(256), 0, stream, x, gw, gb, gbuf);
    hipLaunchKernelGGL(kBl2, dim3(GRID_B), dim3(256), 0, stream, x, comb, gbuf, zbuf);
    hipLaunchKernelGGL(kG2a, dim3(GRID_G), dim3(256), 0, stream, wt, zbuf, mid, out);
    hipLaunchKernelGGL(kD,   dim3(2048),   dim3(256), 0, stream, x, mid, gamma, beta, out);
  } else if (ws_size >= need1){
    hipLaunchKernelGGL(kQ,  dim3(GRID_B), dim3(256), 0, stream, x, gw, gb, gbuf);
    hipLaunchKernelGGL(kBl, dim3(GRID_B), dim3(256), 0, stream, x, comb, gbuf, out);
    hipLaunchKernelGGL(kG,  dim3(GRID_G), dim3(256), 0, stream, wt, mid, out);
    hipLaunchKernelGGL(kD,  dim3(2048),   dim3(256), 0, stream, x, mid, gamma, beta, out);
  } else {
    hipLaunchKernelGGL(kBf, dim3(GRID_B), dim3(256), 0, stream, x, gw, gb, comb, out);
    hipLaunchKernelGGL(kG,  dim3(GRID_G), dim3(256), 0, stream, wt, mid, out);
    hipLaunchKernelGGL(kD,  dim3(2048),   dim3(256), 0, stream, x, mid, gamma, beta, out);
  }
}

// Round 19
// 217.092 us; speedup vs baseline: 1.4860x; 1.4860x over previous
//
#include <hip/hip_runtime.h>

typedef unsigned short u16;
typedef unsigned int   u32;
typedef __attribute__((ext_vector_type(8))) short bfrag8;   // 8 x bf16
typedef __attribute__((ext_vector_type(4))) float f32x4;

#define NSAMP  15552
#define GRID_B 3888    // 3888 blocks * 4 waves * 1 sample = 15552
#define GRID_G 4131    // 4131 blocks * 4 waves * 16 rows = 264384 = NSAMP*17

__device__ __forceinline__ u32 bfr(float f){            // f32 -> bf16 bits, RNE
  u32 u = __float_as_uint(f);
  return (u + 0x7FFFu + ((u >> 16) & 1u)) >> 16;
}
__device__ __forceinline__ u32 packbf(float lo, float hi){
  return bfr(lo) | (bfr(hi) << 16);
}
__device__ __forceinline__ float ubf(u32 v){ return __uint_as_float(v << 16); }
__device__ __forceinline__ float ubfh(u32 v){ return __uint_as_float(v & 0xFFFF0000u); }
__device__ __forceinline__ float sigm(float v){ return 1.0f / (1.0f + __expf(-v)); }
__device__ __forceinline__ float softp(float v){ return (v > 20.f) ? v : log1pf(__expf(v)); }

// ---------------- Kernel A: W transpose->bf16, comb matrix, zero BN acc ----
__global__ void kA(const float* __restrict__ W, const float* __restrict__ al1,
                   const float* __restrict__ al2, const float* __restrict__ w1,
                   const float* __restrict__ w2, const float* __restrict__ a1b,
                   const float* __restrict__ a2b, u16* __restrict__ wt,
                   float* __restrict__ comb, float* __restrict__ mid){
  int idx = blockIdx.x * 256 + threadIdx.x;      // grid 64 -> 16384 elements
  int k = idx >> 7, n = idx & 127;
  wt[n * 128 + k] = (u16)bfr(W[idx]);            // WT[n][k] = W[k][n]
  if (blockIdx.x == 1) mid[threadIdx.x] = 0.f;   // zero BN accumulators (replay-safe)
  if (blockIdx.x == 0){
    float s1 = softp(w1[0]);
    float s2 = softp(w2[0]);
    for (int p = threadIdx.x; p < 289; p += 256){
      int i = p / 17, j = p - i * 17;
      float mij = s1 * (a1b[i*17+j] + sigm(al1[i*17+j])) + s2 * (a2b[i*17+j] + sigm(al2[i*17+j]));
      float mji = s1 * (a1b[j*17+i] + sigm(al1[j*17+i])) + s2 * (a2b[j*17+i] + sigm(al2[j*17+i]));
      comb[i*20 + j] = 0.5f * (mij + mji);
    }
  }
}

// ---------------- Kernel Q: Gram + norms + gates via MFMA (r10-verified) ----
struct __align__(16) QSmem { u16 xb[4][18][136]; };   // 19584 B
__global__ __launch_bounds__(256, 4) void kQ(const float* __restrict__ x,
    const float* __restrict__ gw, const float* __restrict__ gb,
    float* __restrict__ gbuf){
  __shared__ QSmem q;
  const int tid = threadIdx.x;
  const int w  = tid >> 6;
  const int l  = tid & 63;
  const int g4 = l >> 4;
  const int lc = l & 15;
  const int s  = blockIdx.x * 4 + w;
  const float* xs = x + (size_t)s * 2176;

  float2 g2 = *(const float2*)(gw + 2*l);
  *(u32*)&q.xb[w][17][2*l] = packbf(g2.x, g2.y);   // row 17 = gate_w
  #pragma unroll
  for (int j = 0; j < 17; j++){
    float2 v = *(const float2*)(xs + j*128 + 2*l);
    *(u32*)&q.xb[w][j][2*l] = packbf(v.x, v.y);
  }
  __syncthreads();
  __builtin_amdgcn_sched_barrier(0);               // anti-hoist hygiene

  const int rB = 16 + ((lc < 2) ? lc : 1);         // B rows: 16=x16, 17=gate (clamped)
  f32x4 z4 = {0.f,0.f,0.f,0.f};
  f32x4 dg00 = z4, dg01 = z4, dg11 = z4;
  #pragma unroll
  for (int ks = 0; ks < 4; ks++){
    const int ko = ks*32 + (g4 << 3);
    bfrag8 a0 = *(const bfrag8*)&q.xb[w][lc][ko];
    bfrag8 a1 = *(const bfrag8*)&q.xb[w][rB][ko];
    dg00 = __builtin_amdgcn_mfma_f32_16x16x32_bf16(a0, a0, dg00, 0,0,0);
    dg01 = __builtin_amdgcn_mfma_f32_16x16x32_bf16(a0, a1, dg01, 0,0,0);
    dg11 = __builtin_amdgcn_mfma_f32_16x16x32_bf16(a1, a1, dg11, 0,0,0);
  }
  float* gs = gbuf + (size_t)s * 384;
  const float gbv = gb[0];
  #pragma unroll
  for (int r = 0; r < 4; r++){
    const int i = (g4 << 2) + r;
    gs[i*20 + lc] = dg00[r];                       // dot(x_i, x_lc)
    if (lc == 0){ gs[i*20 + 16] = dg01[r]; gs[16*20 + i] = dg01[r]; }
    if (lc == 1){ gs[360 + i] = sigm(dg01[r] + gbv); }
  }
  if ((lc >> 2) == g4){
    float v = dg00[lc & 3];
    gs[340 + lc] = 1.0f / fmaxf(sqrtf(v), 1e-12f);
  }
  if (l == 0) gs[340 + 16] = 1.0f / fmaxf(sqrtf(dg11[0]), 1e-12f);
  if (l == 1) gs[360 + 16] = sigm(dg11[0] + gbv);
}

// ---------------- shared LDS layout for kB variants ----
struct WaveMem {
  float G[17][20];      // Gram dots -> overwritten by A_hat    1360 B
  float scr[64];        // [0..16] inv-norm, [20..36] gate, [40..56] d
};                      // 1616 B
struct BSmem {
  WaveMem wm[4];        // 6464
  float   combs[340];   // 1360  -> 7824 B total
};
static_assert(sizeof(BSmem) <= 81920, "LDS budget");

// ---- common body: loads G/scr from gbuf, computes A_hat, emits z. ZOUT:
// 0 -> f32 into out, 1 -> bf16 into zbuf
template<int ZOUT>
__device__ __forceinline__ void kBl_body(
    const float* __restrict__ x, const float* __restrict__ combg,
    const float* __restrict__ gbuf, float* __restrict__ out,
    u16* __restrict__ zbuf){
  __shared__ BSmem sm;
  const int tid = threadIdx.x;
  const int w  = tid >> 6;
  const int l  = tid & 63;
  const int g4 = l >> 4;
  const int lc = l & 15;

  for (int p = tid; p < 340; p += 256) sm.combs[p] = combg[p];

  WaveMem& M = sm.wm[w];
  float* Mf = (float*)&M.G[0][0];
  const int s = blockIdx.x * 4 + w;
  const float* gs = gbuf + (size_t)s * 384;
  for (int p = l; p < 380; p += 64) Mf[p] = gs[p];

  const float* xs = x + (size_t)s * 2176;
  float2 xr[17];
  #pragma unroll
  for (int j = 0; j < 17; j++) xr[j] = *(const float2*)(xs + j*128 + 2*l);
  __syncthreads();   // (1) comb + G + scr staged

  // P2: A construct + degree
  const float iv16 = M.scr[16], gt16 = M.scr[36];
  const float ivj  = M.scr[lc];
  float av00[4], av01[4], dp0[4];
  #pragma unroll
  for (int r = 0; r < 4; r++){
    const int i0 = (g4 << 2) + r;
    const float iv0 = M.scr[i0], gi0 = M.scr[20 + i0];
    float dyn = (i0 == lc) ? 2.0f : fmaxf(M.G[i0][lc] * iv0 * ivj, 0.f);
    av00[r] = gi0 * sm.combs[i0*20 + lc] + (1.f - gi0) * dyn;
    float dyn16 = fmaxf(M.G[i0][16] * iv0 * iv16, 0.f);
    float a16 = gi0 * sm.combs[i0*20 + 16] + (1.f - gi0) * dyn16;
    av01[r] = (lc == 0) ? a16 : 0.f;
    dp0[r] = av00[r] + av01[r];
  }
  float dyn10 = fmaxf(M.G[16][lc] * iv16 * ivj, 0.f);
  float av10 = gt16 * sm.combs[16*20 + lc] + (1.f - gt16) * dyn10;
  float av11 = (lc == 0) ? (gt16 * sm.combs[16*20 + 16] + (1.f - gt16) * 2.0f) : 0.f;
  float dp1 = av10 + av11;
  #pragma unroll
  for (int m = 1; m <= 8; m <<= 1){
    #pragma unroll
    for (int r = 0; r < 4; r++) dp0[r] += __shfl_xor(dp0[r], m, 64);
    dp1 += __shfl_xor(dp1, m, 64);
  }
  float dd0[4];
  #pragma unroll
  for (int r = 0; r < 4; r++) dd0[r] = rsqrtf(dp0[r] + 1e-6f);
  float dd1 = rsqrtf(dp1 + 1e-6f);
  if (lc == 0){
    #pragma unroll
    for (int r = 0; r < 4; r++) M.scr[40 + (g4<<2) + r] = dd0[r];
  }
  if (l == 0) M.scr[40 + 16] = dd1;
  __syncthreads();   // (2) d ready

  // P3: A_hat in place over G
  const float dj0 = M.scr[40 + lc];
  const float dj1 = M.scr[40 + 16];
  #pragma unroll
  for (int r = 0; r < 4; r++){
    const int i0 = (g4 << 2) + r;
    M.G[i0][lc] = dd0[r] * av00[r] * dj0;
    if (lc == 0) M.G[i0][16] = dd0[r] * av01[r] * dj1;
  }
  if (g4 == 0) M.G[16][lc] = dd1 * av10 * dj0;
  if (l == 0)  M.G[16][16] = dd1 * av11 * dj1;
  __syncthreads();   // (3) A_hat ready

  // P4: z = A_hat @ x
  float* ob = out + (size_t)s * 2176;
  u16*   zb = zbuf + (size_t)s * 2176;
  for (int i = 0; i < 17; i++){
    const float4 a0 = *(const float4*)&M.G[i][0];
    const float4 a1 = *(const float4*)&M.G[i][4];
    const float4 a2 = *(const float4*)&M.G[i][8];
    const float4 a3 = *(const float4*)&M.G[i][12];
    const float a16 = M.G[i][16];
    float zx = a0.x*xr[0].x,  zy = a0.x*xr[0].y;
    zx += a0.y*xr[1].x;  zy += a0.y*xr[1].y;
    zx += a0.z*xr[2].x;  zy += a0.z*xr[2].y;
    zx += a0.w*xr[3].x;  zy += a0.w*xr[3].y;
    zx += a1.x*xr[4].x;  zy += a1.x*xr[4].y;
    zx += a1.y*xr[5].x;  zy += a1.y*xr[5].y;
    zx += a1.z*xr[6].x;  zy += a1.z*xr[6].y;
    zx += a1.w*xr[7].x;  zy += a1.w*xr[7].y;
    zx += a2.x*xr[8].x;  zy += a2.x*xr[8].y;
    zx += a2.y*xr[9].x;  zy += a2.y*xr[9].y;
    zx += a2.z*xr[10].x; zy += a2.z*xr[10].y;
    zx += a2.w*xr[11].x; zy += a2.w*xr[11].y;
    zx += a3.x*xr[12].x; zy += a3.x*xr[12].y;
    zx += a3.y*xr[13].x; zy += a3.y*xr[13].y;
    zx += a3.z*xr[14].x; zy += a3.z*xr[14].y;
    zx += a3.w*xr[15].x; zy += a3.w*xr[15].y;
    zx += a16*xr[16].x;  zy += a16*xr[16].y;
    if (ZOUT == 1){
      *(u32*)&zb[i*128 + 2*l] = packbf(zx, zy);
    } else {
      float2 zv; zv.x = zx; zv.y = zy;
      *(float2*)&ob[i*128 + 2*l] = zv;
    }
  }
}

__global__ __launch_bounds__(256, 4) void kBl2(
    const float* __restrict__ x, const float* __restrict__ combg,
    const float* __restrict__ gbuf, u16* __restrict__ zbuf){
  kBl_body<1>(x, combg, gbuf, nullptr, zbuf);
}
__global__ __launch_bounds__(256, 4) void kBl(
    const float* __restrict__ x, const float* __restrict__ combg,
    const float* __restrict__ gbuf, float* __restrict__ out){
  kBl_body<0>(x, combg, gbuf, out, nullptr);
}

// ---------------- Kernel Bf: monolithic fallback (ws too small; r9-verified) ----
__global__ __launch_bounds__(256, 4) void kBf(
    const float* __restrict__ x, const float* __restrict__ gw,
    const float* __restrict__ gb, const float* __restrict__ combg,
    float* __restrict__ out){
  __shared__ BSmem sm;
  const int tid = threadIdx.x;
  const int w  = tid >> 6;
  const int l  = tid & 63;
  const int g4 = l >> 4;
  const int lc = l & 15;

  for (int p = tid; p < 340; p += 256) sm.combs[p] = combg[p];
  __syncthreads();

  WaveMem& M = sm.wm[w];
  float2 g2 = *(const float2*)(gw + 2*l);
  const float gbv = gb[0];
  const int s = blockIdx.x * 4 + w;
  const float* xs = x + (size_t)s * 2176;
  float2 xr[17];
  #pragma unroll
  for (int j = 0; j < 17; j++) xr[j] = *(const float2*)(xs + j*128 + 2*l);

  #pragma unroll
  for (int i = 0; i < 17; i++){
    float p[17];
    #pragma unroll
    for (int j = i; j < 17; j++)
      p[j-i] = xr[i].x*xr[j].x + xr[i].y*xr[j].y;
    float pg = xr[i].x*g2.x + xr[i].y*g2.y;
    #pragma unroll
    for (int m = 1; m <= 32; m <<= 1){
      #pragma unroll
      for (int j = i; j < 17; j++) p[j-i] += __shfl_xor(p[j-i], m, 64);
      pg += __shfl_xor(pg, m, 64);
    }
    #pragma unroll
    for (int j = i; j < 17; j++){
      if (l == j) M.G[i][j] = p[j-i];
      if (i != j && l == i) M.G[j][i] = p[j-i];
    }
    if (l == i){
      M.scr[i]      = 1.0f / fmaxf(sqrtf(p[0]), 1e-12f);
      M.scr[20 + i] = sigm(pg + gbv);
    }
  }
  __syncthreads();

  const float iv16 = M.scr[16], gt16 = M.scr[36];
  const float ivj  = M.scr[lc];
  float av00[4], av01[4], dp0[4];
  #pragma unroll
  for (int r = 0; r < 4; r++){
    const int i0 = (g4 << 2) + r;
    const float iv0 = M.scr[i0], gi0 = M.scr[20 + i0];
    float dyn = (i0 == lc) ? 2.0f : fmaxf(M.G[i0][lc] * iv0 * ivj, 0.f);
    av00[r] = gi0 * sm.combs[i0*20 + lc] + (1.f - gi0) * dyn;
    float dyn16 = fmaxf(M.G[i0][16] * iv0 * iv16, 0.f);
    float a16 = gi0 * sm.combs[i0*20 + 16] + (1.f - gi0) * dyn16;
    av01[r] = (lc == 0) ? a16 : 0.f;
    dp0[r] = av00[r] + av01[r];
  }
  float dyn10 = fmaxf(M.G[16][lc] * iv16 * ivj, 0.f);
  float av10 = gt16 * sm.combs[16*20 + lc] + (1.f - gt16) * dyn10;
  float av11 = (lc == 0) ? (gt16 * sm.combs[16*20 + 16] + (1.f - gt16) * 2.0f) : 0.f;
  float dp1 = av10 + av11;
  #pragma unroll
  for (int m = 1; m <= 8; m <<= 1){
    #pragma unroll
    for (int r = 0; r < 4; r++) dp0[r] += __shfl_xor(dp0[r], m, 64);
    dp1 += __shfl_xor(dp1, m, 64);
  }
  float dd0[4];
  #pragma unroll
  for (int r = 0; r < 4; r++) dd0[r] = rsqrtf(dp0[r] + 1e-6f);
  float dd1 = rsqrtf(dp1 + 1e-6f);
  if (lc == 0){
    #pragma unroll
    for (int r = 0; r < 4; r++) M.scr[40 + (g4<<2) + r] = dd0[r];
  }
  if (l == 0) M.scr[40 + 16] = dd1;
  __syncthreads();

  const float dj0 = M.scr[40 + lc];
  const float dj1 = M.scr[40 + 16];
  #pragma unroll
  for (int r = 0; r < 4; r++){
    const int i0 = (g4 << 2) + r;
    M.G[i0][lc] = dd0[r] * av00[r] * dj0;
    if (lc == 0) M.G[i0][16] = dd0[r] * av01[r] * dj1;
  }
  if (g4 == 0) M.G[16][lc] = dd1 * av10 * dj0;
  if (l == 0)  M.G[16][16] = dd1 * av11 * dj1;
  __syncthreads();

  float* ob = out + (size_t)s * 2176;
  for (int i = 0; i < 17; i++){
    const float4 a0 = *(const float4*)&M.G[i][0];
    const float4 a1 = *(const float4*)&M.G[i][4];
    const float4 a2 = *(const float4*)&M.G[i][8];
    const float4 a3 = *(const float4*)&M.G[i][12];
    const float a16 = M.G[i][16];
    float zx = a0.x*xr[0].x,  zy = a0.x*xr[0].y;
    zx += a0.y*xr[1].x;  zy += a0.y*xr[1].y;
    zx += a0.z*xr[2].x;  zy += a0.z*xr[2].y;
    zx += a0.w*xr[3].x;  zy += a0.w*xr[3].y;
    zx += a1.x*xr[4].x;  zy += a1.x*xr[4].y;
    zx += a1.y*xr[5].x;  zy += a1.y*xr[5].y;
    zx += a1.z*xr[6].x;  zy += a1.z*xr[6].y;
    zx += a1.w*xr[7].x;  zy += a1.w*xr[7].y;
    zx += a2.x*xr[8].x;  zy += a2.x*xr[8].y;
    zx += a2.y*xr[9].x;  zy += a2.y*xr[9].y;
    zx += a2.z*xr[10].x; zy += a2.z*xr[10].y;
    zx += a2.w*xr[11].x; zy += a2.w*xr[11].y;
    zx += a3.x*xr[12].x; zy += a3.x*xr[12].y;
    zx += a3.y*xr[13].x; zy += a3.y*xr[13].y;
    zx += a3.z*xr[14].x; zy += a3.z*xr[14].y;
    zx += a3.w*xr[15].x; zy += a3.w*xr[15].y;
    zx += a16*xr[16].x;  zy += a16*xr[16].y;
    float2 zv; zv.x = zx; zv.y = zy;
    *(float2*)&ob[i*128 + 2*l] = zv;
  }
}

// ---------------- Kernel G6: coalesced streaming MFMA GEMM (LDS overlay z/h) ----
struct __align__(16) G6Smem {
  u16   zh[4][16][136];  // 17408 B  z tile in -> h tile out (overlay; per-wave)
  float stash[4][256];   // 4096 B
};                       // 21504 B -> 6 blocks/CU (VGPR budget 85 > 52 used)
__global__ __launch_bounds__(256, 6) void kG6(const u16* __restrict__ wtg,
    u16* __restrict__ zbuf, float* __restrict__ part){
  __shared__ G6Smem g;
  const int tid = threadIdx.x;
  const int w  = tid >> 6;
  const int l  = tid & 63;
  const int g4 = l >> 4;
  const int lc = l & 15;
  const int tile = blockIdx.x * 4 + w;           // 4131*4 = 16524 tiles exactly
  u16* zt = zbuf + (size_t)tile * 2048;          // 16 rows * 128 ch

  // P0: coalesced tile load (lane l: bytes [k*1024 + l*16, +16))
  uint4 zc[4];
  #pragma unroll
  for (int k = 0; k < 4; k++)
    zc[k] = *(const uint4*)((const char*)zt + k*1024 + l*16);
  // chunk (k,l) = row k*4 + (l>>4), cols (l&15)*8 .. +8
  #pragma unroll
  for (int k = 0; k < 4; k++)
    *(uint4*)&g.zh[w][k*4 + (l>>4)][(l&15)*8] = zc[k];
  asm volatile("s_waitcnt lgkmcnt(0)" ::: "memory");
  __builtin_amdgcn_sched_barrier(0);             // cross-lane LDS handoff (rule #18)

  // P1: A-fragments from LDS (2-way bank, free). Data lands in regs; the
  // later overlay writes are ordered after these reads by data dependence.
  bfrag8 zf[4];
  #pragma unroll
  for (int ks = 0; ks < 4; ks++)
    zf[ks] = *(const bfrag8*)&g.zh[w][lc][ks*32 + (g4 << 3)];

  // P2: MFMA (B = W^T rows from global; 32 KB, L1/L2-hot)
  f32x4 zero4 = {0.f,0.f,0.f,0.f};
  f32x4 acc[8];
  #pragma unroll
  for (int nf = 0; nf < 8; nf++) acc[nf] = zero4;
  #pragma unroll
  for (int nf = 0; nf < 8; nf++){
    const u16* wr = &wtg[(nf*16 + lc)*128 + (g4 << 3)];
    bfrag8 w0 = *(const bfrag8*)&wr[0];
    bfrag8 w1 = *(const bfrag8*)&wr[32];
    bfrag8 w2 = *(const bfrag8*)&wr[64];
    bfrag8 w3 = *(const bfrag8*)&wr[96];
    acc[nf] = __builtin_amdgcn_mfma_f32_16x16x32_bf16(zf[0], w0, acc[nf], 0,0,0);
    acc[nf] = __builtin_amdgcn_mfma_f32_16x16x32_bf16(zf[1], w1, acc[nf], 0,0,0);
    acc[nf] = __builtin_amdgcn_mfma_f32_16x16x32_bf16(zf[2], w2, acc[nf], 0,0,0);
    acc[nf] = __builtin_amdgcn_mfma_f32_16x16x32_bf16(zf[3], w3, acc[nf], 0,0,0);
  }

  // P3: BN partials (exact f32) + h -> LDS bf16 overlay (hyp1: row 4*g4+r, col nf*16+lc)
  float s[8], q[8];
  #pragma unroll
  for (int nf = 0; nf < 8; nf++){
    float ss = 0.f, qq = 0.f;
    #pragma unroll
    for (int r = 0; r < 4; r++){
      float v = acc[nf][r];
      g.zh[w][4*g4 + r][nf*16 + lc] = (u16)bfr(v);
      ss += v; qq += v*v;
    }
    ss += __shfl_xor(ss, 16, 64); ss += __shfl_xor(ss, 32, 64);
    qq += __shfl_xor(qq, 16, 64); qq += __shfl_xor(qq, 32, 64);
    s[nf] = ss; q[nf] = qq;
  }
  asm volatile("s_waitcnt lgkmcnt(0)" ::: "memory");
  __builtin_amdgcn_sched_barrier(0);             // cross-lane LDS handoff

  // P4: coalesced store (lane l: bytes [k*1024 + l*16, +16) of the tile)
  #pragma unroll
  for (int k = 0; k < 4; k++){
    uint4 pv = *(const uint4*)&g.zh[w][k*4 + (l>>4)][(l&15)*8];
    *(uint4*)((char*)zt + k*1024 + l*16) = pv;   // in-place over own tile
  }

  // P5: BN partial block-reduce, contention-free part store
  if (l < 16){
    #pragma unroll
    for (int nf = 0; nf < 8; nf++){
      g.stash[w][nf*16 + l]       = s[nf];
      g.stash[w][128 + nf*16 + l] = q[nf];
    }
  }
  __syncthreads();
  part[(size_t)blockIdx.x * 256 + tid] =
      g.stash[0][tid] + g.stash[1][tid] + g.stash[2][tid] + g.stash[3][tid];
}

// ---------------- Kernel C: reduce per-block BN partials -> mid ----------------
__global__ __launch_bounds__(256) void kC(const float* __restrict__ part,
    float* __restrict__ mid, int nblk){
  __shared__ float smem[256];
  const int t = threadIdx.x, c = blockIdx.x;     // c = channel slot 0..255
  float acc = 0.f;
  for (int g = t; g < nblk; g += 256) acc += part[(size_t)g * 256 + c];
  smem[t] = acc;
  __syncthreads();
  for (int sft = 128; sft > 0; sft >>= 1){
    if (t < sft) smem[t] += smem[t + sft];
    __syncthreads();
  }
  if (t == 0) mid[c] = smem[0];
}

// ---------------- Kernel G2a: streaming GEMM + atomics (need2 fallback) ----
__global__ __launch_bounds__(256, 4) void kG2a(const u16* __restrict__ wtg,
    const u16* __restrict__ zbuf, float* __restrict__ mid, float* __restrict__ out){
  __shared__ float stash[4][256];
  const int tid = threadIdx.x;
  const int w  = tid >> 6;
  const int l  = tid & 63;
  const int g4 = l >> 4;
  const int lc = l & 15;
  const int R = blockIdx.x * 64 + w * 16;

  const u16* zr = zbuf + (size_t)R * 128;
  f32x4 zero4 = {0.f,0.f,0.f,0.f};
  f32x4 acc[8];
  #pragma unroll
  for (int nf = 0; nf < 8; nf++) acc[nf] = zero4;
  #pragma unroll
  for (int ks = 0; ks < 4; ks++){
    const int ko = ks*32 + (g4 << 3);
    bfrag8 za = *(const bfrag8*)&zr[lc * 128 + ko];
    #pragma unroll
    for (int nf = 0; nf < 8; nf++){
      bfrag8 bw = *(const bfrag8*)&wtg[(nf*16 + lc)*128 + ko];
      acc[nf] = __builtin_amdgcn_mfma_f32_16x16x32_bf16(za, bw, acc[nf], 0,0,0);
    }
  }
  float* hg = out + (size_t)R * 128;
  float s[8], q[8];
  #pragma unroll
  for (int nf = 0; nf < 8; nf++){
    float ss = 0.f, qq = 0.f;
    #pragma unroll
    for (int r = 0; r < 4; r++){
      float v = acc[nf][r];
      hg[(4*g4 + r)*128 + nf*16 + lc] = v;
      ss += v; qq += v*v;
    }
    ss += __shfl_xor(ss, 16, 64); ss += __shfl_xor(ss, 32, 64);
    qq += __shfl_xor(qq, 16, 64); qq += __shfl_xor(qq, 32, 64);
    s[nf] = ss; q[nf] = qq;
  }
  if (l < 16){
    #pragma unroll
    for (int nf = 0; nf < 8; nf++){
      stash[w][nf*16 + l]       = s[nf];
      stash[w][128 + nf*16 + l] = q[nf];
    }
  }
  __syncthreads();
  atomicAdd(&mid[tid], stash[0][tid] + stash[1][tid] + stash[2][tid] + stash[3][tid]);
}

// ---------------- Kernel G: r10 staged variant (fallback, atomics) ----------------
struct __align__(16) GSmem {
  u16 wl[128][132];
  u16 zl[4][16][132];
};
__global__ __launch_bounds__(256, 3) void kG(const u16* __restrict__ wtg,
    float* __restrict__ mid, float* __restrict__ out){
  __shared__ GSmem g;
  const int tid = threadIdx.x;
  const int w  = tid >> 6;
  const int l  = tid & 63;
  const int g4 = l >> 4;
  const int lc = l & 15;

  for (int p = tid; p < 8192; p += 256){
    int n = p >> 6, k2 = (p & 63) * 2;
    *(u32*)&g.wl[n][k2] = ((const u32*)wtg)[p];
  }
  const int R = blockIdx.x * 64 + w * 16;
  float* zg = out + (size_t)R * 128;
  #pragma unroll
  for (int r = 0; r < 16; r++){
    float2 zv = *(const float2*)&zg[r*128 + 2*l];
    *(u32*)&g.zl[w][r][2*l] = packbf(zv.x, zv.y);
  }
  __syncthreads();
  __builtin_amdgcn_sched_barrier(0);

  f32x4 zero4 = {0.f,0.f,0.f,0.f};
  f32x4 acc[8];
  #pragma unroll
  for (int nf = 0; nf < 8; nf++) acc[nf] = zero4;
  #pragma unroll
  for (int ks = 0; ks < 4; ks++){
    const int ko = ks*32 + (g4 << 3);
    bfrag8 za = *(const bfrag8*)&g.zl[w][lc][ko];
    #pragma unroll
    for (int nf = 0; nf < 8; nf++){
      bfrag8 bw = *(const bfrag8*)&g.wl[nf*16 + lc][ko];
      acc[nf] = __builtin_amdgcn_mfma_f32_16x16x32_bf16(za, bw, acc[nf], 0,0,0);
    }
  }

  float s[8], q[8];
  #pragma unroll
  for (int nf = 0; nf < 8; nf++){
    float ss = 0.f, qq = 0.f;
    #pragma unroll
    for (int r = 0; r < 4; r++){
      float v = acc[nf][r];
      zg[(4*g4 + r)*128 + nf*16 + lc] = v;
      ss += v; qq += v*v;
    }
    ss += __shfl_xor(ss, 16, 64); ss += __shfl_xor(ss, 32, 64);
    qq += __shfl_xor(qq, 16, 64); qq += __shfl_xor(qq, 32, 64);
    s[nf] = ss; q[nf] = qq;
  }

  __syncthreads();
  float* stash = (float*)&g.zl[w][0][0];
  if (l < 16){
    #pragma unroll
    for (int nf = 0; nf < 8; nf++){
      stash[nf*16 + l]       = s[nf];
      stash[128 + nf*16 + l] = q[nf];
    }
  }
  __syncthreads();
  float t0 = ((float*)&g.zl[0][0][0])[tid];
  float t1 = ((float*)&g.zl[1][0][0])[tid];
  float t2 = ((float*)&g.zl[2][0][0])[tid];
  float t3 = ((float*)&g.zl[3][0][0])[tid];
  atomicAdd(&mid[tid], t0 + t1 + t2 + t3);
}

// ---------------- Kernel D2: BN + ReLU + residual, h from bf16 buffer ----------------
__global__ __launch_bounds__(256) void kD2(const float* __restrict__ x,
    const float* __restrict__ mid, const float* __restrict__ gamma,
    const float* __restrict__ beta, const u16* __restrict__ hbuf,
    float* __restrict__ out){
  __shared__ float sc[128], sh[128];
  const int t = threadIdx.x;
  if (t < 128){
    const float ic = 1.0f / 264384.0f;     // N*J
    float mean = mid[t] * ic;
    float var  = fmaxf(mid[128 + t] * ic - mean*mean, 0.f);
    float scl  = gamma[t] * rsqrtf(var + 1e-5f);
    sc[t] = scl;
    sh[t] = beta[t] - mean * scl;
  }
  __syncthreads();
  const int total16 = 4230144;             // 33,841,152 / 8 channels per thread-iter
  for (int i = blockIdx.x*256 + t; i < total16; i += 2048*256){
    uint4 hv = ((const uint4*)hbuf)[i];
    float4 x0 = ((const float4*)x)[2*i];
    float4 x1 = ((const float4*)x)[2*i + 1];
    int c0 = (i & 15) << 3;
    float4 r0, r1;
    r0.x = fmaxf(ubf (hv.x)*sc[c0+0] + sh[c0+0], 0.f) + x0.x;
    r0.y = fmaxf(ubfh(hv.x)*sc[c0+1] + sh[c0+1], 0.f) + x0.y;
    r0.z = fmaxf(ubf (hv.y)*sc[c0+2] + sh[c0+2], 0.f) + x0.z;
    r0.w = fmaxf(ubfh(hv.y)*sc[c0+3] + sh[c0+3], 0.f) + x0.w;
    r1.x = fmaxf(ubf (hv.z)*sc[c0+4] + sh[c0+4], 0.f) + x1.x;
    r1.y = fmaxf(ubfh(hv.z)*sc[c0+5] + sh[c0+5], 0.f) + x1.y;
    r1.z = fmaxf(ubf (hv.w)*sc[c0+6] + sh[c0+6], 0.f) + x1.z;
    r1.w = fmaxf(ubfh(hv.w)*sc[c0+7] + sh[c0+7], 0.f) + x1.w;
    ((float4*)out)[2*i]     = r0;
    ((float4*)out)[2*i + 1] = r1;
  }
}

// ---------------- Kernel D: BN + ReLU + residual, h f32 in out (fallback) ----------------
__global__ __launch_bounds__(256) void kD(const float* __restrict__ x,
    const float* __restrict__ mid, const float* __restrict__ gamma,
    const float* __restrict__ beta, float* __restrict__ out){
  __shared__ float sc[128], sh[128];
  const int t = threadIdx.x;
  if (t < 128){
    const float ic = 1.0f / 264384.0f;     // N*J
    float mean = mid[t] * ic;
    float var  = fmaxf(mid[128 + t] * ic - mean*mean, 0.f);
    float scl  = gamma[t] * rsqrtf(var + 1e-5f);
    sc[t] = scl;
    sh[t] = beta[t] - mean * scl;
  }
  __syncthreads();
  const int total = 8460288;               // 33,841,152 / 4
  for (int i = blockIdx.x*256 + t; i < total; i += 2048*256){
    float4 h  = ((const float4*)out)[i];
    float4 xv = ((const float4*)x)[i];
    int c0 = (i & 31) << 2;
    float4 r;
    r.x = fmaxf(h.x*sc[c0+0] + sh[c0+0], 0.f) + xv.x;
    r.y = fmaxf(h.y*sc[c0+1] + sh[c0+1], 0.f) + xv.y;
    r.z = fmaxf(h.z*sc[c0+2] + sh[c0+2], 0.f) + xv.z;
    r.w = fmaxf(h.w*sc[c0+3] + sh[c0+3], 0.f) + xv.w;
    ((float4*)out)[i] = r;
  }
}

extern "C" void kernel_launch(void* const* d_in, const int* in_sizes, int n_in,
                              void* d_out, int out_size, void* d_ws, size_t ws_size,
                              hipStream_t stream){
  (void)in_sizes; (void)n_in; (void)out_size;
  const float* x     = (const float*)d_in[0];
  const float* W     = (const float*)d_in[1];
  // d_in[2] = b : cancelled exactly by training-mode BatchNorm (mean shift)
  const float* al1   = (const float*)d_in[3];
  const float* al2   = (const float*)d_in[4];
  const float* w1    = (const float*)d_in[5];
  const float* w2    = (const float*)d_in[6];
  const float* gw    = (const float*)d_in[7];
  const float* gb    = (const float*)d_in[8];
  const float* gamma = (const float*)d_in[9];
  const float* beta  = (const float*)d_in[10];
  const float* a1b   = (const float*)d_in[11];
  const float* a2b   = (const float*)d_in[12];
  float* out = (float*)d_out;

  float* wsf  = (float*)d_ws;        // comb 384 | wt 8192 | mid 256 | gbuf | zbuf | part
  float* comb = wsf;
  u16*   wt   = (u16*)(wsf + 384);
  float* mid  = wsf + 384 + 8192;
  float* gbuf = wsf + 384 + 8192 + 256;                    // 15552*384 f32 = 23.9 MB
  u16*   zbuf = (u16*)(gbuf + (size_t)NSAMP*384);          // 33,841,152 u16 = 67.7 MB
  float* part = (float*)(zbuf + (size_t)NSAMP*2176);       // 4131*256 f32 = 4.2 MB
  const size_t base  = (size_t)(384 + 8192 + 256) * 4;
  const size_t need1 = base + (size_t)NSAMP*384*4;                         // gbuf path
  const size_t need2 = need1 + (size_t)NSAMP*2176*2;                       // + zbuf path
  const size_t need3 = need2 + (size_t)GRID_G*256*4;                       // + part path

  hipLaunchKernelGGL(kA, dim3(64), dim3(256), 0, stream, W, al1, al2, w1, w2, a1b, a2b, wt, comb, mid);
  if (ws_size >= need3){
    hipLaunchKernelGGL(kQ,   dim3(GRID_B), dim3(256), 0, stream, x, gw, gb, gbuf);
    hipLaunchKernelGGL(kBl2, dim3(GRID_B), dim3(256), 0, stream, x, comb, gbuf, zbuf);
    hipLaunchKernelGGL(kG6,  dim3(GRID_G), dim3(256), 0, stream, wt, zbuf, part);
    hipLaunchKernelGGL(kC,   dim3(256),    dim3(256), 0, stream, part, mid, GRID_G);
    hipLaunchKernelGGL(kD2,  dim3(2048),   dim3(256), 0, stream, x, mid, gamma, beta, zbuf, out);
  } else if (ws_size >= need2){
    hipLaunchKernelGGL(kQ,   dim3(GRID_B), dim3(256), 0, stream, x, gw, gb, gbuf);
    hipLaunchKernelGGL(kBl2, dim3(GRID_B), dim3(256), 0, stream, x, comb, gbuf, zbuf);
    hipLaunchKernelGGL(kG2a, dim3(GRID_G), dim3(256), 0, stream, wt, zbuf, mid, out);
    hipLaunchKernelGGL(kD,   dim3(2048),   dim3(256), 0, stream, x, mid, gamma, beta, out);
  } else if (ws_size >= need1){
    hipLaunchKernelGGL(kQ,  dim3(GRID_B), dim3(256), 0, stream, x, gw, gb, gbuf);
    hipLaunchKernelGGL(kBl, dim3(GRID_B), dim3(256), 0, stream, x, comb, gbuf, out);
    hipLaunchKernelGGL(kG,  dim3(GRID_G), dim3(256), 0, stream, wt, mid, out);
    hipLaunchKernelGGL(kD,  dim3(2048),   dim3(256), 0, stream, x, mid, gamma, beta, out);
  } else {
    hipLaunchKernelGGL(kBf, dim3(GRID_B), dim3(256), 0, stream, x, gw, gb, comb, out);
    hipLaunchKernelGGL(kG,  dim3(GRID_G), dim3(256), 0, stream, wt, mid, out);
    hipLaunchKernelGGL(kD,  dim3(2048),   dim3(256), 0, stream, x, mid, gamma, beta, out);
  }
}

// Round 21
// 216.549 us; speedup vs baseline: 1.4897x; 1.0025x over previous
//
#include <hip/hip_runtime.h>

typedef unsigned short u16;
typedef unsigned int   u32;
typedef __attribute__((ext_vector_type(8))) short bfrag8;   // 8 x bf16
typedef __attribute__((ext_vector_type(4))) float f32x4;

#define NSAMP  15552
#define GRID_B 3888    // 3888 blocks * 4 waves * 1 sample = 15552
#define GRID_G 4131    // 4131 blocks * 4 waves * 16 rows = 264384 = NSAMP*17

__device__ __forceinline__ u32 bfr(float f){            // f32 -> bf16 bits, RNE
  u32 u = __float_as_uint(f);
  return (u + 0x7FFFu + ((u >> 16) & 1u)) >> 16;
}
__device__ __forceinline__ u32 packbf(float lo, float hi){
  return bfr(lo) | (bfr(hi) << 16);
}
__device__ __forceinline__ float ubf(u32 v){ return __uint_as_float(v << 16); }
__device__ __forceinline__ float ubfh(u32 v){ return __uint_as_float(v & 0xFFFF0000u); }
__device__ __forceinline__ float sigm(float v){ return 1.0f / (1.0f + __expf(-v)); }
__device__ __forceinline__ float softp(float v){ return (v > 20.f) ? v : log1pf(__expf(v)); }

// ---------------- Kernel A: W transpose->bf16, comb matrix, zero BN acc ----
__global__ void kA(const float* __restrict__ W, const float* __restrict__ al1,
                   const float* __restrict__ al2, const float* __restrict__ w1,
                   const float* __restrict__ w2, const float* __restrict__ a1b,
                   const float* __restrict__ a2b, u16* __restrict__ wt,
                   float* __restrict__ comb, float* __restrict__ mid){
  int idx = blockIdx.x * 256 + threadIdx.x;      // grid 64 -> 16384 elements
  int k = idx >> 7, n = idx & 127;
  wt[n * 128 + k] = (u16)bfr(W[idx]);            // WT[n][k] = W[k][n]
  if (blockIdx.x == 1) mid[threadIdx.x] = 0.f;   // zero BN accumulators (replay-safe)
  if (blockIdx.x == 0){
    float s1 = softp(w1[0]);
    float s2 = softp(w2[0]);
    for (int p = threadIdx.x; p < 289; p += 256){
      int i = p / 17, j = p - i * 17;
      float mij = s1 * (a1b[i*17+j] + sigm(al1[i*17+j])) + s2 * (a2b[i*17+j] + sigm(al2[i*17+j]));
      float mji = s1 * (a1b[j*17+i] + sigm(al1[j*17+i])) + s2 * (a2b[j*17+i] + sigm(al2[j*17+i]));
      comb[i*20 + j] = 0.5f * (mij + mji);
    }
  }
}

// ---------------- Kernel Q: Gram + norms + gates via MFMA (r10-verified) ----
struct __align__(16) QSmem { u16 xb[4][18][136]; };   // 19584 B
__global__ __launch_bounds__(256, 4) void kQ(const float* __restrict__ x,
    const float* __restrict__ gw, const float* __restrict__ gb,
    float* __restrict__ gbuf){
  __shared__ QSmem q;
  const int tid = threadIdx.x;
  const int w  = tid >> 6;
  const int l  = tid & 63;
  const int g4 = l >> 4;
  const int lc = l & 15;
  const int s  = blockIdx.x * 4 + w;
  const float* xs = x + (size_t)s * 2176;

  float2 g2 = *(const float2*)(gw + 2*l);
  *(u32*)&q.xb[w][17][2*l] = packbf(g2.x, g2.y);   // row 17 = gate_w
  #pragma unroll
  for (int j = 0; j < 17; j++){
    float2 v = *(const float2*)(xs + j*128 + 2*l);
    *(u32*)&q.xb[w][j][2*l] = packbf(v.x, v.y);
  }
  __syncthreads();
  __builtin_amdgcn_sched_barrier(0);               // anti-hoist hygiene

  const int rB = 16 + ((lc < 2) ? lc : 1);         // B rows: 16=x16, 17=gate (clamped)
  f32x4 z4 = {0.f,0.f,0.f,0.f};
  f32x4 dg00 = z4, dg01 = z4, dg11 = z4;
  #pragma unroll
  for (int ks = 0; ks < 4; ks++){
    const int ko = ks*32 + (g4 << 3);
    bfrag8 a0 = *(const bfrag8*)&q.xb[w][lc][ko];
    bfrag8 a1 = *(const bfrag8*)&q.xb[w][rB][ko];
    dg00 = __builtin_amdgcn_mfma_f32_16x16x32_bf16(a0, a0, dg00, 0,0,0);
    dg01 = __builtin_amdgcn_mfma_f32_16x16x32_bf16(a0, a1, dg01, 0,0,0);
    dg11 = __builtin_amdgcn_mfma_f32_16x16x32_bf16(a1, a1, dg11, 0,0,0);
  }
  float* gs = gbuf + (size_t)s * 384;
  const float gbv = gb[0];
  #pragma unroll
  for (int r = 0; r < 4; r++){
    const int i = (g4 << 2) + r;
    gs[i*20 + lc] = dg00[r];                       // dot(x_i, x_lc)
    if (lc == 0){ gs[i*20 + 16] = dg01[r]; gs[16*20 + i] = dg01[r]; }
    if (lc == 1){ gs[360 + i] = sigm(dg01[r] + gbv); }
  }
  if ((lc >> 2) == g4){
    float v = dg00[lc & 3];
    gs[340 + lc] = 1.0f / fmaxf(sqrtf(v), 1e-12f);
  }
  if (l == 0) gs[340 + 16] = 1.0f / fmaxf(sqrtf(dg11[0]), 1e-12f);
  if (l == 1) gs[360 + 16] = sigm(dg11[0] + gbv);
}

// ---------------- shared LDS layout for kB variants ----
struct WaveMem {
  float G[17][20];      // Gram dots -> overwritten by A_hat    1360 B
  float scr[64];        // [0..16] inv-norm, [20..36] gate, [40..56] d
};                      // 1616 B
struct BSmem {
  WaveMem wm[4];        // 6464
  float   combs[340];   // 1360  -> 7824 B total
};
static_assert(sizeof(BSmem) <= 81920, "LDS budget");

// ---- common body: loads G/scr from gbuf, computes A_hat, emits z. ZOUT:
// 0 -> f32 into out, 1 -> bf16 into zbuf
template<int ZOUT>
__device__ __forceinline__ void kBl_body(
    const float* __restrict__ x, const float* __restrict__ combg,
    const float* __restrict__ gbuf, float* __restrict__ out,
    u16* __restrict__ zbuf){
  __shared__ BSmem sm;
  const int tid = threadIdx.x;
  const int w  = tid >> 6;
  const int l  = tid & 63;
  const int g4 = l >> 4;
  const int lc = l & 15;

  for (int p = tid; p < 340; p += 256) sm.combs[p] = combg[p];

  WaveMem& M = sm.wm[w];
  float* Mf = (float*)&M.G[0][0];
  const int s = blockIdx.x * 4 + w;
  const float* gs = gbuf + (size_t)s * 384;
  for (int p = l; p < 380; p += 64) Mf[p] = gs[p];

  const float* xs = x + (size_t)s * 2176;
  float2 xr[17];
  #pragma unroll
  for (int j = 0; j < 17; j++) xr[j] = *(const float2*)(xs + j*128 + 2*l);
  __syncthreads();   // (1) comb + G + scr staged

  // P2: A construct + degree
  const float iv16 = M.scr[16], gt16 = M.scr[36];
  const float ivj  = M.scr[lc];
  float av00[4], av01[4], dp0[4];
  #pragma unroll
  for (int r = 0; r < 4; r++){
    const int i0 = (g4 << 2) + r;
    const float iv0 = M.scr[i0], gi0 = M.scr[20 + i0];
    float dyn = (i0 == lc) ? 2.0f : fmaxf(M.G[i0][lc] * iv0 * ivj, 0.f);
    av00[r] = gi0 * sm.combs[i0*20 + lc] + (1.f - gi0) * dyn;
    float dyn16 = fmaxf(M.G[i0][16] * iv0 * iv16, 0.f);
    float a16 = gi0 * sm.combs[i0*20 + 16] + (1.f - gi0) * dyn16;
    av01[r] = (lc == 0) ? a16 : 0.f;
    dp0[r] = av00[r] + av01[r];
  }
  float dyn10 = fmaxf(M.G[16][lc] * iv16 * ivj, 0.f);
  float av10 = gt16 * sm.combs[16*20 + lc] + (1.f - gt16) * dyn10;
  float av11 = (lc == 0) ? (gt16 * sm.combs[16*20 + 16] + (1.f - gt16) * 2.0f) : 0.f;
  float dp1 = av10 + av11;
  #pragma unroll
  for (int m = 1; m <= 8; m <<= 1){
    #pragma unroll
    for (int r = 0; r < 4; r++) dp0[r] += __shfl_xor(dp0[r], m, 64);
    dp1 += __shfl_xor(dp1, m, 64);
  }
  float dd0[4];
  #pragma unroll
  for (int r = 0; r < 4; r++) dd0[r] = rsqrtf(dp0[r] + 1e-6f);
  float dd1 = rsqrtf(dp1 + 1e-6f);
  if (lc == 0){
    #pragma unroll
    for (int r = 0; r < 4; r++) M.scr[40 + (g4<<2) + r] = dd0[r];
  }
  if (l == 0) M.scr[40 + 16] = dd1;
  __syncthreads();   // (2) d ready

  // P3: A_hat in place over G
  const float dj0 = M.scr[40 + lc];
  const float dj1 = M.scr[40 + 16];
  #pragma unroll
  for (int r = 0; r < 4; r++){
    const int i0 = (g4 << 2) + r;
    M.G[i0][lc] = dd0[r] * av00[r] * dj0;
    if (lc == 0) M.G[i0][16] = dd0[r] * av01[r] * dj1;
  }
  if (g4 == 0) M.G[16][lc] = dd1 * av10 * dj0;
  if (l == 0)  M.G[16][16] = dd1 * av11 * dj1;
  __syncthreads();   // (3) A_hat ready

  // P4: z = A_hat @ x
  float* ob = out + (size_t)s * 2176;
  u16*   zb = zbuf + (size_t)s * 2176;
  for (int i = 0; i < 17; i++){
    const float4 a0 = *(const float4*)&M.G[i][0];
    const float4 a1 = *(const float4*)&M.G[i][4];
    const float4 a2 = *(const float4*)&M.G[i][8];
    const float4 a3 = *(const float4*)&M.G[i][12];
    const float a16 = M.G[i][16];
    float zx = a0.x*xr[0].x,  zy = a0.x*xr[0].y;
    zx += a0.y*xr[1].x;  zy += a0.y*xr[1].y;
    zx += a0.z*xr[2].x;  zy += a0.z*xr[2].y;
    zx += a0.w*xr[3].x;  zy += a0.w*xr[3].y;
    zx += a1.x*xr[4].x;  zy += a1.x*xr[4].y;
    zx += a1.y*xr[5].x;  zy += a1.y*xr[5].y;
    zx += a1.z*xr[6].x;  zy += a1.z*xr[6].y;
    zx += a1.w*xr[7].x;  zy += a1.w*xr[7].y;
    zx += a2.x*xr[8].x;  zy += a2.x*xr[8].y;
    zx += a2.y*xr[9].x;  zy += a2.y*xr[9].y;
    zx += a2.z*xr[10].x; zy += a2.z*xr[10].y;
    zx += a2.w*xr[11].x; zy += a2.w*xr[11].y;
    zx += a3.x*xr[12].x; zy += a3.x*xr[12].y;
    zx += a3.y*xr[13].x; zy += a3.y*xr[13].y;
    zx += a3.z*xr[14].x; zy += a3.z*xr[14].y;
    zx += a3.w*xr[15].x; zy += a3.w*xr[15].y;
    zx += a16*xr[16].x;  zy += a16*xr[16].y;
    if (ZOUT == 1){
      *(u32*)&zb[i*128 + 2*l] = packbf(zx, zy);
    } else {
      float2 zv; zv.x = zx; zv.y = zy;
      *(float2*)&ob[i*128 + 2*l] = zv;
    }
  }
}

__global__ __launch_bounds__(256, 4) void kBl2(
    const float* __restrict__ x, const float* __restrict__ combg,
    const float* __restrict__ gbuf, u16* __restrict__ zbuf){
  kBl_body<1>(x, combg, gbuf, nullptr, zbuf);
}
__global__ __launch_bounds__(256, 4) void kBl(
    const float* __restrict__ x, const float* __restrict__ combg,
    const float* __restrict__ gbuf, float* __restrict__ out){
  kBl_body<0>(x, combg, gbuf, out, nullptr);
}

// ---------------- Kernel Bf: monolithic fallback (ws too small; r9-verified) ----
__global__ __launch_bounds__(256, 4) void kBf(
    const float* __restrict__ x, const float* __restrict__ gw,
    const float* __restrict__ gb, const float* __restrict__ combg,
    float* __restrict__ out){
  __shared__ BSmem sm;
  const int tid = threadIdx.x;
  const int w  = tid >> 6;
  const int l  = tid & 63;
  const int g4 = l >> 4;
  const int lc = l & 15;

  for (int p = tid; p < 340; p += 256) sm.combs[p] = combg[p];
  __syncthreads();

  WaveMem& M = sm.wm[w];
  float2 g2 = *(const float2*)(gw + 2*l);
  const float gbv = gb[0];
  const int s = blockIdx.x * 4 + w;
  const float* xs = x + (size_t)s * 2176;
  float2 xr[17];
  #pragma unroll
  for (int j = 0; j < 17; j++) xr[j] = *(const float2*)(xs + j*128 + 2*l);

  #pragma unroll
  for (int i = 0; i < 17; i++){
    float p[17];
    #pragma unroll
    for (int j = i; j < 17; j++)
      p[j-i] = xr[i].x*xr[j].x + xr[i].y*xr[j].y;
    float pg = xr[i].x*g2.x + xr[i].y*g2.y;
    #pragma unroll
    for (int m = 1; m <= 32; m <<= 1){
      #pragma unroll
      for (int j = i; j < 17; j++) p[j-i] += __shfl_xor(p[j-i], m, 64);
      pg += __shfl_xor(pg, m, 64);
    }
    #pragma unroll
    for (int j = i; j < 17; j++){
      if (l == j) M.G[i][j] = p[j-i];
      if (i != j && l == i) M.G[j][i] = p[j-i];
    }
    if (l == i){
      M.scr[i]      = 1.0f / fmaxf(sqrtf(p[0]), 1e-12f);
      M.scr[20 + i] = sigm(pg + gbv);
    }
  }
  __syncthreads();

  const float iv16 = M.scr[16], gt16 = M.scr[36];
  const float ivj  = M.scr[lc];
  float av00[4], av01[4], dp0[4];
  #pragma unroll
  for (int r = 0; r < 4; r++){
    const int i0 = (g4 << 2) + r;
    const float iv0 = M.scr[i0], gi0 = M.scr[20 + i0];
    float dyn = (i0 == lc) ? 2.0f : fmaxf(M.G[i0][lc] * iv0 * ivj, 0.f);
    av00[r] = gi0 * sm.combs[i0*20 + lc] + (1.f - gi0) * dyn;
    float dyn16 = fmaxf(M.G[i0][16] * iv0 * iv16, 0.f);
    float a16 = gi0 * sm.combs[i0*20 + 16] + (1.f - gi0) * dyn16;
    av01[r] = (lc == 0) ? a16 : 0.f;
    dp0[r] = av00[r] + av01[r];
  }
  float dyn10 = fmaxf(M.G[16][lc] * iv16 * ivj, 0.f);
  float av10 = gt16 * sm.combs[16*20 + lc] + (1.f - gt16) * dyn10;
  float av11 = (lc == 0) ? (gt16 * sm.combs[16*20 + 16] + (1.f - gt16) * 2.0f) : 0.f;
  float dp1 = av10 + av11;
  #pragma unroll
  for (int m = 1; m <= 8; m <<= 1){
    #pragma unroll
    for (int r = 0; r < 4; r++) dp0[r] += __shfl_xor(dp0[r], m, 64);
    dp1 += __shfl_xor(dp1, m, 64);
  }
  float dd0[4];
  #pragma unroll
  for (int r = 0; r < 4; r++) dd0[r] = rsqrtf(dp0[r] + 1e-6f);
  float dd1 = rsqrtf(dp1 + 1e-6f);
  if (lc == 0){
    #pragma unroll
    for (int r = 0; r < 4; r++) M.scr[40 + (g4<<2) + r] = dd0[r];
  }
  if (l == 0) M.scr[40 + 16] = dd1;
  __syncthreads();

  const float dj0 = M.scr[40 + lc];
  const float dj1 = M.scr[40 + 16];
  #pragma unroll
  for (int r = 0; r < 4; r++){
    const int i0 = (g4 << 2) + r;
    M.G[i0][lc] = dd0[r] * av00[r] * dj0;
    if (lc == 0) M.G[i0][16] = dd0[r] * av01[r] * dj1;
  }
  if (g4 == 0) M.G[16][lc] = dd1 * av10 * dj0;
  if (l == 0)  M.G[16][16] = dd1 * av11 * dj1;
  __syncthreads();

  float* ob = out + (size_t)s * 2176;
  for (int i = 0; i < 17; i++){
    const float4 a0 = *(const float4*)&M.G[i][0];
    const float4 a1 = *(const float4*)&M.G[i][4];
    const float4 a2 = *(const float4*)&M.G[i][8];
    const float4 a3 = *(const float4*)&M.G[i][12];
    const float a16 = M.G[i][16];
    float zx = a0.x*xr[0].x,  zy = a0.x*xr[0].y;
    zx += a0.y*xr[1].x;  zy += a0.y*xr[1].y;
    zx += a0.z*xr[2].x;  zy += a0.z*xr[2].y;
    zx += a0.w*xr[3].x;  zy += a0.w*xr[3].y;
    zx += a1.x*xr[4].x;  zy += a1.x*xr[4].y;
    zx += a1.y*xr[5].x;  zy += a1.y*xr[5].y;
    zx += a1.z*xr[6].x;  zy += a1.z*xr[6].y;
    zx += a1.w*xr[7].x;  zy += a1.w*xr[7].y;
    zx += a2.x*xr[8].x;  zy += a2.x*xr[8].y;
    zx += a2.y*xr[9].x;  zy += a2.y*xr[9].y;
    zx += a2.z*xr[10].x; zy += a2.z*xr[10].y;
    zx += a2.w*xr[11].x; zy += a2.w*xr[11].y;
    zx += a3.x*xr[12].x; zy += a3.x*xr[12].y;
    zx += a3.y*xr[13].x; zy += a3.y*xr[13].y;
    zx += a3.z*xr[14].x; zy += a3.z*xr[14].y;
    zx += a3.w*xr[15].x; zy += a3.w*xr[15].y;
    zx += a16*xr[16].x;  zy += a16*xr[16].y;
    float2 zv; zv.x = zx; zv.y = zy;
    *(float2*)&ob[i*128 + 2*l] = zv;
  }
}

// ---------------- Kernel G6: coalesced streaming MFMA GEMM (LDS overlay z/h) ----
struct __align__(16) G6Smem {
  u16   zh[4][16][136];  // 17408 B  z tile in -> h tile out (overlay; per-wave)
  float stash[4][256];   // 4096 B
};                       // 21504 B -> 6 blocks/CU
__global__ __launch_bounds__(256, 6) void kG6(const u16* __restrict__ wtg,
    u16* __restrict__ zbuf, float* __restrict__ part){
  __shared__ G6Smem g;
  const int tid = threadIdx.x;
  const int w  = tid >> 6;
  const int l  = tid & 63;
  const int g4 = l >> 4;
  const int lc = l & 15;
  const int tile = blockIdx.x * 4 + w;           // 4131*4 = 16524 tiles exactly
  u16* zt = zbuf + (size_t)tile * 2048;          // 16 rows * 128 ch

  uint4 zc[4];
  #pragma unroll
  for (int k = 0; k < 4; k++)
    zc[k] = *(const uint4*)((const char*)zt + k*1024 + l*16);
  #pragma unroll
  for (int k = 0; k < 4; k++)
    *(uint4*)&g.zh[w][k*4 + (l>>4)][(l&15)*8] = zc[k];
  asm volatile("s_waitcnt lgkmcnt(0)" ::: "memory");
  __builtin_amdgcn_sched_barrier(0);             // cross-lane LDS handoff (rule #18)

  bfrag8 zf[4];
  #pragma unroll
  for (int ks = 0; ks < 4; ks++)
    zf[ks] = *(const bfrag8*)&g.zh[w][lc][ks*32 + (g4 << 3)];

  f32x4 zero4 = {0.f,0.f,0.f,0.f};
  f32x4 acc[8];
  #pragma unroll
  for (int nf = 0; nf < 8; nf++) acc[nf] = zero4;
  #pragma unroll
  for (int nf = 0; nf < 8; nf++){
    const u16* wr = &wtg[(nf*16 + lc)*128 + (g4 << 3)];
    bfrag8 w0 = *(const bfrag8*)&wr[0];
    bfrag8 w1 = *(const bfrag8*)&wr[32];
    bfrag8 w2 = *(const bfrag8*)&wr[64];
    bfrag8 w3 = *(const bfrag8*)&wr[96];
    acc[nf] = __builtin_amdgcn_mfma_f32_16x16x32_bf16(zf[0], w0, acc[nf], 0,0,0);
    acc[nf] = __builtin_amdgcn_mfma_f32_16x16x32_bf16(zf[1], w1, acc[nf], 0,0,0);
    acc[nf] = __builtin_amdgcn_mfma_f32_16x16x32_bf16(zf[2], w2, acc[nf], 0,0,0);
    acc[nf] = __builtin_amdgcn_mfma_f32_16x16x32_bf16(zf[3], w3, acc[nf], 0,0,0);
  }

  float s[8], q[8];
  #pragma unroll
  for (int nf = 0; nf < 8; nf++){
    float ss = 0.f, qq = 0.f;
    #pragma unroll
    for (int r = 0; r < 4; r++){
      float v = acc[nf][r];
      g.zh[w][4*g4 + r][nf*16 + lc] = (u16)bfr(v);
      ss += v; qq += v*v;
    }
    ss += __shfl_xor(ss, 16, 64); ss += __shfl_xor(ss, 32, 64);
    qq += __shfl_xor(qq, 16, 64); qq += __shfl_xor(qq, 32, 64);
    s[nf] = ss; q[nf] = qq;
  }
  asm volatile("s_waitcnt lgkmcnt(0)" ::: "memory");
  __builtin_amdgcn_sched_barrier(0);             // cross-lane LDS handoff

  #pragma unroll
  for (int k = 0; k < 4; k++){
    uint4 pv = *(const uint4*)&g.zh[w][k*4 + (l>>4)][(l&15)*8];
    *(uint4*)((char*)zt + k*1024 + l*16) = pv;   // in-place over own tile
  }

  if (l < 16){
    #pragma unroll
    for (int nf = 0; nf < 8; nf++){
      g.stash[w][nf*16 + l]       = s[nf];
      g.stash[w][128 + nf*16 + l] = q[nf];
    }
  }
  __syncthreads();
  part[(size_t)blockIdx.x * 256 + tid] =
      g.stash[0][tid] + g.stash[1][tid] + g.stash[2][tid] + g.stash[3][tid];
}

// ---------------- Kernel C: reduce per-block BN partials -> mid ----------------
__global__ __launch_bounds__(256) void kC(const float* __restrict__ part,
    float* __restrict__ mid, int nblk){
  __shared__ float smem[256];
  const int t = threadIdx.x, c = blockIdx.x;     // c = channel slot 0..255
  float acc = 0.f;
  for (int g = t; g < nblk; g += 256) acc += part[(size_t)g * 256 + c];
  smem[t] = acc;
  __syncthreads();
  for (int sft = 128; sft > 0; sft >>= 1){
    if (t < sft) smem[t] += smem[t + sft];
    __syncthreads();
  }
  if (t == 0) mid[c] = smem[0];
}

// ---------------- Kernel G2a: streaming GEMM + atomics (need2 fallback) ----
__global__ __launch_bounds__(256, 4) void kG2a(const u16* __restrict__ wtg,
    const u16* __restrict__ zbuf, float* __restrict__ mid, float* __restrict__ out){
  __shared__ float stash[4][256];
  const int tid = threadIdx.x;
  const int w  = tid >> 6;
  const int l  = tid & 63;
  const int g4 = l >> 4;
  const int lc = l & 15;
  const int R = blockIdx.x * 64 + w * 16;

  const u16* zr = zbuf + (size_t)R * 128;
  f32x4 zero4 = {0.f,0.f,0.f,0.f};
  f32x4 acc[8];
  #pragma unroll
  for (int nf = 0; nf < 8; nf++) acc[nf] = zero4;
  #pragma unroll
  for (int ks = 0; ks < 4; ks++){
    const int ko = ks*32 + (g4 << 3);
    bfrag8 za = *(const bfrag8*)&zr[lc * 128 + ko];
    #pragma unroll
    for (int nf = 0; nf < 8; nf++){
      bfrag8 bw = *(const bfrag8*)&wtg[(nf*16 + lc)*128 + ko];
      acc[nf] = __builtin_amdgcn_mfma_f32_16x16x32_bf16(za, bw, acc[nf], 0,0,0);
    }
  }
  float* hg = out + (size_t)R * 128;
  float s[8], q[8];
  #pragma unroll
  for (int nf = 0; nf < 8; nf++){
    float ss = 0.f, qq = 0.f;
    #pragma unroll
    for (int r = 0; r < 4; r++){
      float v = acc[nf][r];
      hg[(4*g4 + r)*128 + nf*16 + lc] = v;
      ss += v; qq += v*v;
    }
    ss += __shfl_xor(ss, 16, 64); ss += __shfl_xor(ss, 32, 64);
    qq += __shfl_xor(qq, 16, 64); qq += __shfl_xor(qq, 32, 64);
    s[nf] = ss; q[nf] = qq;
  }
  if (l < 16){
    #pragma unroll
    for (int nf = 0; nf < 8; nf++){
      stash[w][nf*16 + l]       = s[nf];
      stash[w][128 + nf*16 + l] = q[nf];
    }
  }
  __syncthreads();
  atomicAdd(&mid[tid], stash[0][tid] + stash[1][tid] + stash[2][tid] + stash[3][tid]);
}

// ---------------- Kernel G: r10 staged variant (fallback, atomics) ----------------
struct __align__(16) GSmem {
  u16 wl[128][132];
  u16 zl[4][16][132];
};
__global__ __launch_bounds__(256, 3) void kG(const u16* __restrict__ wtg,
    float* __restrict__ mid, float* __restrict__ out){
  __shared__ GSmem g;
  const int tid = threadIdx.x;
  const int w  = tid >> 6;
  const int l  = tid & 63;
  const int g4 = l >> 4;
  const int lc = l & 15;

  for (int p = tid; p < 8192; p += 256){
    int n = p >> 6, k2 = (p & 63) * 2;
    *(u32*)&g.wl[n][k2] = ((const u32*)wtg)[p];
  }
  const int R = blockIdx.x * 64 + w * 16;
  float* zg = out + (size_t)R * 128;
  #pragma unroll
  for (int r = 0; r < 16; r++){
    float2 zv = *(const float2*)&zg[r*128 + 2*l];
    *(u32*)&g.zl[w][r][2*l] = packbf(zv.x, zv.y);
  }
  __syncthreads();
  __builtin_amdgcn_sched_barrier(0);

  f32x4 zero4 = {0.f,0.f,0.f,0.f};
  f32x4 acc[8];
  #pragma unroll
  for (int nf = 0; nf < 8; nf++) acc[nf] = zero4;
  #pragma unroll
  for (int ks = 0; ks < 4; ks++){
    const int ko = ks*32 + (g4 << 3);
    bfrag8 za = *(const bfrag8*)&g.zl[w][lc][ko];
    #pragma unroll
    for (int nf = 0; nf < 8; nf++){
      bfrag8 bw = *(const bfrag8*)&g.wl[nf*16 + lc][ko];
      acc[nf] = __builtin_amdgcn_mfma_f32_16x16x32_bf16(za, bw, acc[nf], 0,0,0);
    }
  }

  float s[8], q[8];
  #pragma unroll
  for (int nf = 0; nf < 8; nf++){
    float ss = 0.f, qq = 0.f;
    #pragma unroll
    for (int r = 0; r < 4; r++){
      float v = acc[nf][r];
      zg[(4*g4 + r)*128 + nf*16 + lc] = v;
      ss += v; qq += v*v;
    }
    ss += __shfl_xor(ss, 16, 64); ss += __shfl_xor(ss, 32, 64);
    qq += __shfl_xor(qq, 16, 64); qq += __shfl_xor(qq, 32, 64);
    s[nf] = ss; q[nf] = qq;
  }

  __syncthreads();
  float* stash = (float*)&g.zl[w][0][0];
  if (l < 16){
    #pragma unroll
    for (int nf = 0; nf < 8; nf++){
      stash[nf*16 + l]       = s[nf];
      stash[128 + nf*16 + l] = q[nf];
    }
  }
  __syncthreads();
  float t0 = ((float*)&g.zl[0][0][0])[tid];
  float t1 = ((float*)&g.zl[1][0][0])[tid];
  float t2 = ((float*)&g.zl[2][0][0])[tid];
  float t3 = ((float*)&g.zl[3][0][0])[tid];
  atomicAdd(&mid[tid], t0 + t1 + t2 + t3);
}

// ---------------- Kernel D2: BN + ReLU + residual, h from bf16 buffer ----------------
__global__ __launch_bounds__(256) void kD2(const float* __restrict__ x,
    const float* __restrict__ mid, const float* __restrict__ gamma,
    const float* __restrict__ beta, const u16* __restrict__ hbuf,
    float* __restrict__ out){
  __shared__ float sc[128], sh[128];
  const int t = threadIdx.x;
  if (t < 128){
    const float ic = 1.0f / 264384.0f;     // N*J
    float mean = mid[t] * ic;
    float var  = fmaxf(mid[128 + t] * ic - mean*mean, 0.f);
    float scl  = gamma[t] * rsqrtf(var + 1e-5f);
    sc[t] = scl;
    sh[t] = beta[t] - mean * scl;
  }
  __syncthreads();
  const int total16 = 4230144;             // 33,841,152 / 8 channels per thread-iter
  for (int i = blockIdx.x*256 + t; i < total16; i += 2048*256){
    uint4 hv = ((const uint4*)hbuf)[i];
    float4 x0 = ((const float4*)x)[2*i];
    float4 x1 = ((const float4*)x)[2*i + 1];
    int c0 = (i & 15) << 3;
    float4 r0, r1;
    r0.x = fmaxf(ubf (hv.x)*sc[c0+0] + sh[c0+0], 0.f) + x0.x;
    r0.y = fmaxf(ubfh(hv.x)*sc[c0+1] + sh[c0+1], 0.f) + x0.y;
    r0.z = fmaxf(ubf (hv.y)*sc[c0+2] + sh[c0+2], 0.f) + x0.z;
    r0.w = fmaxf(ubfh(hv.y)*sc[c0+3] + sh[c0+3], 0.f) + x0.w;
    r1.x = fmaxf(ubf (hv.z)*sc[c0+4] + sh[c0+4], 0.f) + x1.x;
    r1.y = fmaxf(ubfh(hv.z)*sc[c0+5] + sh[c0+5], 0.f) + x1.y;
    r1.z = fmaxf(ubf (hv.w)*sc[c0+6] + sh[c0+6], 0.f) + x1.z;
    r1.w = fmaxf(ubfh(hv.w)*sc[c0+7] + sh[c0+7], 0.f) + x1.w;
    ((float4*)out)[2*i]     = r0;
    ((float4*)out)[2*i + 1] = r1;
  }
}

// ---------------- Kernel D: BN + ReLU + residual, h f32 in out (fallback) ----------------
__global__ __launch_bounds__(256) void kD(const float* __restrict__ x,
    const float* __restrict__ mid, const float* __restrict__ gamma,
    const float* __restrict__ beta, float* __restrict__ out){
  __shared__ float sc[128], sh[128];
  const int t = threadIdx.x;
  if (t < 128){
    const float ic = 1.0f / 264384.0f;     // N*J
    float mean = mid[t] * ic;
    float var  = fmaxf(mid[128 + t] * ic - mean*mean, 0.f);
    float scl  = gamma[t] * rsqrtf(var + 1e-5f);
    sc[t] = scl;
    sh[t] = beta[t] - mean * scl;
  }
  __syncthreads();
  const int total = 8460288;               // 33,841,152 / 4
  for (int i = blockIdx.x*256 + t; i < total; i += 2048*256){
    float4 h  = ((const float4*)out)[i];
    float4 xv = ((const float4*)x)[i];
    int c0 = (i & 31) << 2;
    float4 r;
    r.x = fmaxf(h.x*sc[c0+0] + sh[c0+0], 0.f) + xv.x;
    r.y = fmaxf(h.y*sc[c0+1] + sh[c0+1], 0.f) + xv.y;
    r.z = fmaxf(h.z*sc[c0+2] + sh[c0+2], 0.f) + xv.z;
    r.w = fmaxf(h.w*sc[c0+3] + sh[c0+3], 0.f) + xv.w;
    ((float4*)out)[i] = r;
  }
}

extern "C" void kernel_launch(void* const* d_in, const int* in_sizes, int n_in,
                              void* d_out, int out_size, void* d_ws, size_t ws_size,
                              hipStream_t stream){
  (void)in_sizes; (void)n_in; (void)out_size;
  const float* x     = (const float*)d_in[0];
  const float* W     = (const float*)d_in[1];
  // d_in[2] = b : cancelled exactly by training-mode BatchNorm (mean shift)
  const float* al1   = (const float*)d_in[3];
  const float* al2   = (const float*)d_in[4];
  const float* w1    = (const float*)d_in[5];
  const float* w2    = (const float*)d_in[6];
  const float* gw    = (const float*)d_in[7];
  const float* gb    = (const float*)d_in[8];
  const float* gamma = (const float*)d_in[9];
  const float* beta  = (const float*)d_in[10];
  const float* a1b   = (const float*)d_in[11];
  const float* a2b   = (const float*)d_in[12];
  float* out = (float*)d_out;

  float* wsf  = (float*)d_ws;        // comb 384 | wt 8192 | mid 256 | gbuf | zbuf | part
  float* comb = wsf;
  u16*   wt   = (u16*)(wsf + 384);
  float* mid  = wsf + 384 + 8192;
  float* gbuf = wsf + 384 + 8192 + 256;                    // 15552*384 f32 = 23.9 MB
  u16*   zbuf = (u16*)(gbuf + (size_t)NSAMP*384);          // 33,841,152 u16 = 67.7 MB
  float* part = (float*)(zbuf + (size_t)NSAMP*2176);       // 4131*256 f32 = 4.2 MB
  const size_t base  = (size_t)(384 + 8192 + 256) * 4;
  const size_t need1 = base + (size_t)NSAMP*384*4;                         // gbuf path
  const size_t need2 = need1 + (size_t)NSAMP*2176*2;                       // + zbuf path
  const size_t need3 = need2 + (size_t)GRID_G*256*4;                       // + part path

  hipLaunchKernelGGL(kA, dim3(64), dim3(256), 0, stream, W, al1, al2, w1, w2, a1b, a2b, wt, comb, mid);
  if (ws_size >= need3){
    hipLaunchKernelGGL(kQ,   dim3(GRID_B), dim3(256), 0, stream, x, gw, gb, gbuf);
    hipLaunchKernelGGL(kBl2, dim3(GRID_B), dim3(256), 0, stream, x, comb, gbuf, zbuf);
    hipLaunchKernelGGL(kG6,  dim3(GRID_G), dim3(256), 0, stream, wt, zbuf, part);
    hipLaunchKernelGGL(kC,   dim3(256),    dim3(256), 0, stream, part, mid, GRID_G);
    hipLaunchKernelGGL(kD2,  dim3(2048),   dim3(256), 0, stream, x, mid, gamma, beta, zbuf, out);
  } else if (ws_size >= need2){
    hipLaunchKernelGGL(kQ,   dim3(GRID_B), dim3(256), 0, stream, x, gw, gb, gbuf);
    hipLaunchKernelGGL(kBl2, dim3(GRID_B), dim3(256), 0, stream, x, comb, gbuf, zbuf);
    hipLaunchKernelGGL(kG2a, dim3(GRID_G), dim3(256), 0, stream, wt, zbuf, mid, out);
    hipLaunchKernelGGL(kD,   dim3(2048),   dim3(256), 0, stream, x, mid, gamma, beta, out);
  } else if (ws_size >= need1){
    hipLaunchKernelGGL(kQ,  dim3(GRID_B), dim3(256), 0, stream, x, gw, gb, gbuf);
    hipLaunchKernelGGL(kBl, dim3(GRID_B), dim3(256), 0, stream, x, comb, gbuf, out);
    hipLaunchKernelGGL(kG,  dim3(GRID_G), dim3(256), 0, stream, wt, mid, out);
    hipLaunchKernelGGL(kD,  dim3(2048),   dim3(256), 0, stream, x, mid, gamma, beta, out);
  } else {
    hipLaunchKernelGGL(kBf, dim3(GRID_B), dim3(256), 0, stream, x, gw, gb, comb, out);
    hipLaunchKernelGGL(kG,  dim3(GRID_G), dim3(256), 0, stream, wt, mid, out);
    hipLaunchKernelGGL(kD,  dim3(2048),   dim3(256), 0, stream, x, mid, gamma, beta, out);
  }
}